// Round 1
// baseline (12110.437 us; speedup 1.0000x reference)
//
#include <hip/hip_runtime.h>

#define NEG 0.2f

// C[N x 128] = A[N x K] @ W[K x 128], optionally accumulating into C.
// Block: 256 threads handles 16 rows x 128 cols; thread -> col j, row parity r,
// computes 8 rows. A tile staged in LDS (broadcast reads), W from L2.
template <int K, bool ACC>
__global__ __launch_bounds__(256) void gemm128_k(const float* __restrict__ A,
                                                 const float* __restrict__ W,
                                                 float* __restrict__ C, int N) {
    __shared__ float As[16 * K];
    const int j = threadIdx.x & 127;
    const int r = threadIdx.x >> 7;
    const int row0 = blockIdx.x << 4;
    for (int idx = threadIdx.x; idx < 16 * K; idx += 256) {
        int rr = idx / K, kk = idx - rr * K;
        int row = row0 + rr;
        As[idx] = (row < N) ? A[(size_t)row * K + kk] : 0.f;
    }
    __syncthreads();
    float acc[8];
#pragma unroll
    for (int i = 0; i < 8; i++) acc[i] = 0.f;
    for (int k = 0; k < K; k++) {
        float w = W[(k << 7) + j];
#pragma unroll
        for (int i = 0; i < 8; i++) acc[i] += As[(r + (i << 1)) * K + k] * w;
    }
#pragma unroll
    for (int i = 0; i < 8; i++) {
        int row = row0 + r + (i << 1);
        if (row < N) {
            if (ACC)
                C[((size_t)row << 7) + j] += acc[i];
            else
                C[((size_t)row << 7) + j] = acc[i];
        }
    }
}

// el/er for H=4, D=32, feat row stride 128. One thread per (node, head).
__global__ __launch_bounds__(256) void eler_k(const float* __restrict__ feat,
                                              const float* __restrict__ al,
                                              const float* __restrict__ ar,
                                              float* __restrict__ el,
                                              float* __restrict__ er, int N) {
    int idx = blockIdx.x * blockDim.x + threadIdx.x;
    if (idx >= N * 4) return;
    int n = idx >> 2, h = idx & 3;
    const float* f = feat + ((size_t)n << 7) + (h << 5);
    const float* a = al + (h << 5);
    const float* b = ar + (h << 5);
    float sl = 0.f, sr = 0.f;
#pragma unroll
    for (int d = 0; d < 32; d++) {
        float v = f[d];
        sl += v * a[d];
        sr += v * b[d];
    }
    el[idx] = sl;
    er[idx] = sr;
}

// Pass 1: accumulate softmax denominators per (dst, head).
template <int H>
__global__ __launch_bounds__(256) void edge_denom_k(const int* __restrict__ src,
                                                    const int* __restrict__ dst,
                                                    const float* __restrict__ el,
                                                    const float* __restrict__ er,
                                                    float* __restrict__ denom, int E) {
    int idx = blockIdx.x * blockDim.x + threadIdx.x;
    if (idx >= E * H) return;
    int e = idx / H, h = idx - e * H;
    int s = src[e], d = dst[e];
    float x = el[s * H + h] + er[d * H + h];
    x = x > 0.f ? x : NEG * x;
    atomicAdd(&denom[d * H + h], expf(x));
}

// Pass 2 (H=4, D=32): 4 threads per edge, one head each; float4 gather of
// feat[src] and 32 atomic adds into rst[dst].
__global__ __launch_bounds__(256) void edge_agg_k(const int* __restrict__ src,
                                                  const int* __restrict__ dst,
                                                  const float* __restrict__ el,
                                                  const float* __restrict__ er,
                                                  const float* __restrict__ denom,
                                                  const float* __restrict__ feat,
                                                  float* __restrict__ rst, int E) {
    int idx = blockIdx.x * blockDim.x + threadIdx.x;
    int e = idx >> 2;
    if (e >= E) return;
    int h = idx & 3;
    int s = src[e], d = dst[e];
    float x = el[(s << 2) + h] + er[(d << 2) + h];
    x = x > 0.f ? x : NEG * x;
    float alpha = expf(x) / denom[(d << 2) + h];
    const float4* fs = (const float4*)(feat + ((size_t)s << 7) + (h << 5));
    float* rd = rst + ((size_t)d << 7) + (h << 5);
#pragma unroll
    for (int q = 0; q < 8; q++) {
        float4 v = fs[q];
        atomicAdd(rd + (q << 2) + 0, v.x * alpha);
        atomicAdd(rd + (q << 2) + 1, v.y * alpha);
        atomicAdd(rd + (q << 2) + 2, v.z * alpha);
        atomicAdd(rd + (q << 2) + 3, v.w * alpha);
    }
}

__global__ __launch_bounds__(256) void bias_relu_k(float* __restrict__ y,
                                                   const float* __restrict__ b,
                                                   int total) {
    int idx = blockIdx.x * blockDim.x + threadIdx.x;
    if (idx >= total) return;
    float v = y[idx] + b[idx & 127];
    y[idx] = v > 0.f ? v : 0.f;
}

// Layer 3: feat3 = h3 @ W3 (128 -> 6) plus el3/er3 (D=1), per node.
__global__ __launch_bounds__(256) void feat3_k(const float* __restrict__ h3,
                                               const float* __restrict__ W3,
                                               const float* __restrict__ al3,
                                               const float* __restrict__ ar3,
                                               float* __restrict__ feat3,
                                               float* __restrict__ el3,
                                               float* __restrict__ er3, int N) {
    int n = blockIdx.x * blockDim.x + threadIdx.x;
    if (n >= N) return;
    const float4* a = (const float4*)(h3 + ((size_t)n << 7));
    float f[6];
#pragma unroll
    for (int h = 0; h < 6; h++) f[h] = 0.f;
    for (int k4 = 0; k4 < 32; k4++) {
        float4 v = a[k4];
        int k = k4 << 2;
#pragma unroll
        for (int h = 0; h < 6; h++) {
            f[h] += v.x * W3[(k + 0) * 6 + h] + v.y * W3[(k + 1) * 6 + h] +
                    v.z * W3[(k + 2) * 6 + h] + v.w * W3[(k + 3) * 6 + h];
        }
    }
#pragma unroll
    for (int h = 0; h < 6; h++) {
        feat3[n * 6 + h] = f[h];
        el3[n * 6 + h] = f[h] * al3[h];
        er3[n * 6 + h] = f[h] * ar3[h];
    }
}

// Layer 3 aggregation: one thread per edge, 6 heads, D=1.
__global__ __launch_bounds__(256) void edge_agg6_k(const int* __restrict__ src,
                                                   const int* __restrict__ dst,
                                                   const float* __restrict__ el,
                                                   const float* __restrict__ er,
                                                   const float* __restrict__ denom,
                                                   const float* __restrict__ feat,
                                                   float* __restrict__ rst, int E) {
    int e = blockIdx.x * blockDim.x + threadIdx.x;
    if (e >= E) return;
    int s = src[e], d = dst[e];
#pragma unroll
    for (int h = 0; h < 6; h++) {
        float x = el[s * 6 + h] + er[d * 6 + h];
        x = x > 0.f ? x : NEG * x;
        float alpha = expf(x) / denom[d * 6 + h];
        atomicAdd(&rst[d * 6 + h], feat[s * 6 + h] * alpha);
    }
}

// Final: rst3 + h3@resW3 + b3, mean over 6 heads -> out[n].
__global__ __launch_bounds__(256) void final_k(const float* __restrict__ rst3,
                                               const float* __restrict__ h3,
                                               const float* __restrict__ resW3,
                                               const float* __restrict__ b3,
                                               float* __restrict__ out, int N) {
    int n = blockIdx.x * blockDim.x + threadIdx.x;
    if (n >= N) return;
    float r[6];
#pragma unroll
    for (int h = 0; h < 6; h++) r[h] = rst3[n * 6 + h] + b3[h];
    const float4* a = (const float4*)(h3 + ((size_t)n << 7));
    for (int k4 = 0; k4 < 32; k4++) {
        float4 v = a[k4];
        int k = k4 << 2;
#pragma unroll
        for (int h = 0; h < 6; h++)
            r[h] += v.x * resW3[(k + 0) * 6 + h] + v.y * resW3[(k + 1) * 6 + h] +
                    v.z * resW3[(k + 2) * 6 + h] + v.w * resW3[(k + 3) * 6 + h];
    }
    float m = 0.f;
#pragma unroll
    for (int h = 0; h < 6; h++) m += r[h];
    out[n] = m * (1.f / 6.f);
}

extern "C" void kernel_launch(void* const* d_in, const int* in_sizes, int n_in,
                              void* d_out, int out_size, void* d_ws, size_t ws_size,
                              hipStream_t stream) {
    const float* x = (const float*)d_in[0];
    const int* src = (const int*)d_in[1];
    const int* dst = (const int*)d_in[2];
    const float* W1 = (const float*)d_in[3];
    const float* al1 = (const float*)d_in[4];
    const float* ar1 = (const float*)d_in[5];
    const float* b1 = (const float*)d_in[6];
    const float* W2 = (const float*)d_in[7];
    const float* al2 = (const float*)d_in[8];
    const float* ar2 = (const float*)d_in[9];
    const float* b2 = (const float*)d_in[10];
    const float* resW2 = (const float*)d_in[11];
    const float* W3 = (const float*)d_in[12];
    const float* al3 = (const float*)d_in[13];
    const float* ar3 = (const float*)d_in[14];
    const float* b3 = (const float*)d_in[15];
    const float* resW3 = (const float*)d_in[16];
    float* out = (float*)d_out;

    const int N = in_sizes[0] / 64;
    const int E = in_sizes[1];

    float* ws = (float*)d_ws;
    float* feat = ws;                          // N*128 (layer3 reuses first N*6)
    float* h2 = feat + (size_t)N * 128;        // N*128
    float* h3 = h2 + (size_t)N * 128;          // N*128
    float* denom1 = h3 + (size_t)N * 128;      // N*4
    float* denom2 = denom1 + (size_t)N * 4;    // N*4
    float* denom3 = denom2 + (size_t)N * 4;    // N*6
    float* rst3 = denom3 + (size_t)N * 6;      // N*6
    float* el = rst3 + (size_t)N * 6;          // N*6 (reused per layer)
    float* er = el + (size_t)N * 6;            // N*6

    // Zero everything that gets atomically accumulated (h2..rst3 contiguous).
    hipMemsetAsync(h2, 0, sizeof(float) * ((size_t)N * 256 + (size_t)N * 20), stream);

    const int gN16 = (N + 15) / 16;
    const int gNH = (N * 4 + 255) / 256;
    const int gEH4 = (int)(((size_t)E * 4 + 255) / 256);
    const int gEH6 = (int)(((size_t)E * 6 + 255) / 256);
    const int gE = (E + 255) / 256;
    const int gNM = (int)(((size_t)N * 128 + 255) / 256);
    const int gNv = (N + 255) / 256;

    // ---- Layer 1: 64 -> (4,32), relu, no residual ----
    gemm128_k<64, false><<<gN16, 256, 0, stream>>>(x, W1, feat, N);
    eler_k<<<gNH, 256, 0, stream>>>(feat, al1, ar1, el, er, N);
    edge_denom_k<4><<<gEH4, 256, 0, stream>>>(src, dst, el, er, denom1, E);
    edge_agg_k<<<gEH4, 256, 0, stream>>>(src, dst, el, er, denom1, feat, h2, E);
    bias_relu_k<<<gNM, 256, 0, stream>>>(h2, b1, N * 128);

    // ---- Layer 2: 128 -> (4,32), relu, residual ----
    gemm128_k<128, false><<<gN16, 256, 0, stream>>>(h2, W2, feat, N);
    eler_k<<<gNH, 256, 0, stream>>>(feat, al2, ar2, el, er, N);
    edge_denom_k<4><<<gEH4, 256, 0, stream>>>(src, dst, el, er, denom2, E);
    edge_agg_k<<<gEH4, 256, 0, stream>>>(src, dst, el, er, denom2, feat, h3, E);
    gemm128_k<128, true><<<gN16, 256, 0, stream>>>(h2, resW2, h3, N);  // += residual
    bias_relu_k<<<gNM, 256, 0, stream>>>(h3, b2, N * 128);

    // ---- Layer 3: 128 -> (6,1), no act, residual, mean over heads ----
    feat3_k<<<gNv, 256, 0, stream>>>(h3, W3, al3, ar3, feat, el, er, N);
    edge_denom_k<6><<<gEH6, 256, 0, stream>>>(src, dst, el, er, denom3, E);
    edge_agg6_k<<<gE, 256, 0, stream>>>(src, dst, el, er, denom3, feat, rst3, E);
    final_k<<<gNv, 256, 0, stream>>>(rst3, h3, resW3, b3, out, N);
}

// Round 2
// 534.280 us; speedup vs baseline: 22.6668x; 22.6668x over previous
//
#include <hip/hip_runtime.h>

#define NEG 0.2f

// C[N x 128] = A[N x K] @ W[K x 128].
// EPI 0: C = acc.  EPI 2: C = relu(C + acc + bias[j])  (residual fused).
template <int K, int EPI>
__global__ __launch_bounds__(256) void gemm128_k(const float* __restrict__ A,
                                                 const float* __restrict__ W,
                                                 const float* __restrict__ bias,
                                                 float* __restrict__ C, int N) {
    __shared__ float As[16 * K];
    const int j = threadIdx.x & 127;
    const int r = threadIdx.x >> 7;
    const int row0 = blockIdx.x << 4;
    for (int idx = threadIdx.x; idx < 16 * K; idx += 256) {
        int rr = idx / K, kk = idx - rr * K;
        int row = row0 + rr;
        As[idx] = (row < N) ? A[(size_t)row * K + kk] : 0.f;
    }
    __syncthreads();
    float acc[8];
#pragma unroll
    for (int i = 0; i < 8; i++) acc[i] = 0.f;
    for (int k = 0; k < K; k++) {
        float w = W[(k << 7) + j];
#pragma unroll
        for (int i = 0; i < 8; i++) acc[i] += As[(r + (i << 1)) * K + k] * w;
    }
#pragma unroll
    for (int i = 0; i < 8; i++) {
        int row = row0 + r + (i << 1);
        if (row < N) {
            size_t o = ((size_t)row << 7) + j;
            if (EPI == 0) {
                C[o] = acc[i];
            } else {
                float v = C[o] + acc[i] + bias[j];
                C[o] = v > 0.f ? v : 0.f;
            }
        }
    }
}

// el/er for H=4, D=32, feat row stride 128. One thread per (node, head).
__global__ __launch_bounds__(256) void eler_k(const float* __restrict__ feat,
                                              const float* __restrict__ al,
                                              const float* __restrict__ ar,
                                              float* __restrict__ el,
                                              float* __restrict__ er, int N) {
    int idx = blockIdx.x * blockDim.x + threadIdx.x;
    if (idx >= N * 4) return;
    int n = idx >> 2, h = idx & 3;
    const float* f = feat + ((size_t)n << 7) + (h << 5);
    const float* a = al + (h << 5);
    const float* b = ar + (h << 5);
    float sl = 0.f, sr = 0.f;
#pragma unroll
    for (int d = 0; d < 32; d++) {
        float v = f[d];
        sl += v * a[d];
        sr += v * b[d];
    }
    el[idx] = sl;
    er[idx] = sr;
}

// ---------------- CSR build (dst-sorted) ----------------
__global__ __launch_bounds__(256) void count_k(const int* __restrict__ dst,
                                               int* __restrict__ deg, int E) {
    int e = blockIdx.x * 256 + threadIdx.x;
    if (e < E) atomicAdd(&deg[dst[e]], 1);
}

__global__ __launch_bounds__(256) void scan1_k(const int* __restrict__ deg,
                                               int* __restrict__ row_ptr,
                                               int* __restrict__ bsum, int N) {
    __shared__ int tmp[256];
    int i = blockIdx.x * 256 + threadIdx.x;
    int v = (i < N) ? deg[i] : 0;
    tmp[threadIdx.x] = v;
    __syncthreads();
    for (int off = 1; off < 256; off <<= 1) {
        int t = (threadIdx.x >= off) ? tmp[threadIdx.x - off] : 0;
        __syncthreads();
        tmp[threadIdx.x] += t;
        __syncthreads();
    }
    if (i < N) row_ptr[i] = tmp[threadIdx.x] - v;  // exclusive
    if (threadIdx.x == 255) bsum[blockIdx.x] = tmp[255];
}

__global__ __launch_bounds__(256) void scan2_k(int* __restrict__ bsum, int nb) {
    __shared__ int tmp[256];
    int v = (threadIdx.x < nb) ? bsum[threadIdx.x] : 0;
    tmp[threadIdx.x] = v;
    __syncthreads();
    for (int off = 1; off < 256; off <<= 1) {
        int t = (threadIdx.x >= off) ? tmp[threadIdx.x - off] : 0;
        __syncthreads();
        tmp[threadIdx.x] += t;
        __syncthreads();
    }
    if (threadIdx.x < nb) bsum[threadIdx.x] = tmp[threadIdx.x] - v;  // exclusive
}

__global__ __launch_bounds__(256) void scan3_k(int* __restrict__ row_ptr,
                                               const int* __restrict__ bsum,
                                               int N, int E) {
    int i = blockIdx.x * 256 + threadIdx.x;
    if (i < N) row_ptr[i] += bsum[i >> 8];
    if (i == 0) row_ptr[N] = E;
}

__global__ __launch_bounds__(256) void fill_k(const int* __restrict__ src,
                                              const int* __restrict__ dst,
                                              const int* __restrict__ row_ptr,
                                              int* __restrict__ cursor,
                                              int* __restrict__ csr_src, int E) {
    int e = blockIdx.x * 256 + threadIdx.x;
    if (e >= E) return;
    int d = dst[e];
    int pos = row_ptr[d] + atomicAdd(&cursor[d], 1);
    csr_src[pos] = src[e];
}

// ---------------- Pull aggregation (H=4, D=32) ----------------
// One 128-thread block per dst node; thread j -> feature col j, head j>>5.
// Fuses softmax denominator; BR fuses bias+relu (layer 1, no residual).
template <bool BR>
__global__ __launch_bounds__(128) void pull_agg_k(const int* __restrict__ row_ptr,
                                                  const int* __restrict__ csr_src,
                                                  const float* __restrict__ el,
                                                  const float* __restrict__ er,
                                                  const float* __restrict__ feat,
                                                  const float* __restrict__ bias,
                                                  float* __restrict__ outp, int N) {
    int n = blockIdx.x;
    int j = threadIdx.x;
    int h = j >> 5;
    float erd = er[(n << 2) + h];
    int beg = row_ptr[n], end = row_ptr[n + 1];
    float acc = 0.f, den = 0.f;
    for (int p = beg; p < end; p++) {
        int s = csr_src[p];
        float x = el[(s << 2) + h] + erd;
        x = x > 0.f ? x : NEG * x;
        float w = __expf(x);
        den += w;
        acc += w * feat[((size_t)s << 7) + j];
    }
    float v = acc / den;  // den >= 1 edge (self-loops)
    if (BR) {
        v += bias[j];
        v = v > 0.f ? v : 0.f;
    }
    outp[((size_t)n << 7) + j] = v;
}

// Layer 3: feat3 = h3 @ W3 (128 -> 6), per node.
__global__ __launch_bounds__(256) void feat3_k(const float* __restrict__ h3,
                                               const float* __restrict__ W3,
                                               float* __restrict__ feat3, int N) {
    int n = blockIdx.x * blockDim.x + threadIdx.x;
    if (n >= N) return;
    const float4* a = (const float4*)(h3 + ((size_t)n << 7));
    float f[6];
#pragma unroll
    for (int h = 0; h < 6; h++) f[h] = 0.f;
    for (int k4 = 0; k4 < 32; k4++) {
        float4 v = a[k4];
        int k = k4 << 2;
#pragma unroll
        for (int h = 0; h < 6; h++) {
            f[h] += v.x * W3[(k + 0) * 6 + h] + v.y * W3[(k + 1) * 6 + h] +
                    v.z * W3[(k + 2) * 6 + h] + v.w * W3[(k + 3) * 6 + h];
        }
    }
#pragma unroll
    for (int h = 0; h < 6; h++) feat3[n * 6 + h] = f[h];
}

// Layer 3 pull + residual + bias + head-mean. One thread per node.
// D=1 so el[s,h] = feat3[s,h]*al3[h], er[d,h] = feat3[d,h]*ar3[h].
__global__ __launch_bounds__(256) void pull_final6_k(const int* __restrict__ row_ptr,
                                                     const int* __restrict__ csr_src,
                                                     const float* __restrict__ feat3,
                                                     const float* __restrict__ al3,
                                                     const float* __restrict__ ar3,
                                                     const float* __restrict__ h3,
                                                     const float* __restrict__ resW3,
                                                     const float* __restrict__ b3,
                                                     float* __restrict__ out, int N) {
    int n = blockIdx.x * blockDim.x + threadIdx.x;
    if (n >= N) return;
    float a3[6], r3[6], fd[6], acc[6], den[6];
#pragma unroll
    for (int h = 0; h < 6; h++) {
        a3[h] = al3[h];
        r3[h] = ar3[h];
        fd[h] = feat3[n * 6 + h];
        acc[h] = 0.f;
        den[h] = 0.f;
    }
    int beg = row_ptr[n], end = row_ptr[n + 1];
    for (int p = beg; p < end; p++) {
        int s = csr_src[p];
#pragma unroll
        for (int h = 0; h < 6; h++) {
            float fs = feat3[s * 6 + h];
            float x = fs * a3[h] + fd[h] * r3[h];
            x = x > 0.f ? x : NEG * x;
            float w = __expf(x);
            den[h] += w;
            acc[h] += w * fs;
        }
    }
    float r[6];
#pragma unroll
    for (int h = 0; h < 6; h++) r[h] = acc[h] / den[h] + b3[h];
    const float4* a = (const float4*)(h3 + ((size_t)n << 7));
    for (int k4 = 0; k4 < 32; k4++) {
        float4 v = a[k4];
        int k = k4 << 2;
#pragma unroll
        for (int h = 0; h < 6; h++)
            r[h] += v.x * resW3[(k + 0) * 6 + h] + v.y * resW3[(k + 1) * 6 + h] +
                    v.z * resW3[(k + 2) * 6 + h] + v.w * resW3[(k + 3) * 6 + h];
    }
    float m = 0.f;
#pragma unroll
    for (int h = 0; h < 6; h++) m += r[h];
    out[n] = m * (1.f / 6.f);
}

extern "C" void kernel_launch(void* const* d_in, const int* in_sizes, int n_in,
                              void* d_out, int out_size, void* d_ws, size_t ws_size,
                              hipStream_t stream) {
    const float* x = (const float*)d_in[0];
    const int* src = (const int*)d_in[1];
    const int* dst = (const int*)d_in[2];
    const float* W1 = (const float*)d_in[3];
    const float* al1 = (const float*)d_in[4];
    const float* ar1 = (const float*)d_in[5];
    const float* b1 = (const float*)d_in[6];
    const float* W2 = (const float*)d_in[7];
    const float* al2 = (const float*)d_in[8];
    const float* ar2 = (const float*)d_in[9];
    const float* b2 = (const float*)d_in[10];
    const float* resW2 = (const float*)d_in[11];
    const float* W3 = (const float*)d_in[12];
    const float* al3 = (const float*)d_in[13];
    const float* ar3 = (const float*)d_in[14];
    const float* b3 = (const float*)d_in[15];
    const float* resW3 = (const float*)d_in[16];
    float* out = (float*)d_out;

    const int N = in_sizes[0] / 64;
    const int E = in_sizes[1];

    // ---- workspace layout ----
    float* ws = (float*)d_ws;
    float* feat = ws;                        // N*128
    float* h2 = feat + (size_t)N * 128;      // N*128
    float* h3 = h2 + (size_t)N * 128;        // N*128
    float* el = h3 + (size_t)N * 128;        // N*4  (layer 1/2)
    float* er = el + (size_t)N * 4;          // N*4
    float* feat3 = el;                       // N*6 aliases el/er (free in layer 3)
    int* ip = (int*)(er + (size_t)N * 4);
    int* deg = ip;                           // N
    int* cursor = deg + N;                   // N   (memset with deg)
    int* row_ptr = cursor + N;               // N+1
    int* bsum = row_ptr + N + 1;             // 256
    int* csr_src = bsum + 256;               // E

    const int gE = (E + 255) / 256;
    const int gN = (N + 255) / 256;
    const int gN16 = (N + 15) / 16;
    const int gNH = (N * 4 + 255) / 256;
    const int nb = gN;  // scan blocks (N/256 <= 256)

    // ---- build dst-CSR (shared by all 3 layers) ----
    hipMemsetAsync(deg, 0, sizeof(int) * 2 * N, stream);
    count_k<<<gE, 256, 0, stream>>>(dst, deg, E);
    scan1_k<<<nb, 256, 0, stream>>>(deg, row_ptr, bsum, N);
    scan2_k<<<1, 256, 0, stream>>>(bsum, nb);
    scan3_k<<<gN, 256, 0, stream>>>(row_ptr, bsum, N, E);
    fill_k<<<gE, 256, 0, stream>>>(src, dst, row_ptr, cursor, csr_src, E);

    // ---- Layer 1: 64 -> (4,32), relu, no residual ----
    gemm128_k<64, 0><<<gN16, 256, 0, stream>>>(x, W1, nullptr, feat, N);
    eler_k<<<gNH, 256, 0, stream>>>(feat, al1, ar1, el, er, N);
    pull_agg_k<true><<<N, 128, 0, stream>>>(row_ptr, csr_src, el, er, feat, b1, h2, N);

    // ---- Layer 2: 128 -> (4,32), relu, residual ----
    gemm128_k<128, 0><<<gN16, 256, 0, stream>>>(h2, W2, nullptr, feat, N);
    eler_k<<<gNH, 256, 0, stream>>>(feat, al2, ar2, el, er, N);
    pull_agg_k<false><<<N, 128, 0, stream>>>(row_ptr, csr_src, el, er, feat, nullptr, h3, N);
    // h3 = relu(h3 + h2@resW2 + b2)
    gemm128_k<128, 2><<<gN16, 256, 0, stream>>>(h2, resW2, b2, h3, N);

    // ---- Layer 3: 128 -> (6,1), no act, residual, mean over heads ----
    feat3_k<<<gN, 256, 0, stream>>>(h3, W3, feat3, N);
    pull_final6_k<<<gN, 256, 0, stream>>>(row_ptr, csr_src, feat3, al3, ar3, h3,
                                          resW3, b3, out, N);
}

// Round 3
// 459.023 us; speedup vs baseline: 26.3831x; 1.1640x over previous
//
#include <hip/hip_runtime.h>

#define NEG 0.2f

// ---------------- GEMM: C[N x 128] = A[N x K] @ W[K x 128] ----------------
// Block 256 threads -> 64 rows x 128 cols. Thread: rows rg*8..rg*8+7
// (rg = tid>>5), cols 4c..4c+3 (c = tid&31). A tile in LDS (float4 reads),
// W streamed as float4 (L1/L2-hot, reused by all blocks).
// EPI 0: C = acc.  EPI 2: C = relu(C + acc + bias[j]) (residual fused).
template <int K, int EPI>
__global__ __launch_bounds__(256) void gemm128_k(const float* __restrict__ A,
                                                 const float* __restrict__ W,
                                                 const float* __restrict__ bias,
                                                 float* __restrict__ C, int N) {
    __shared__ float As[64 * K];
    const int c = threadIdx.x & 31;
    const int rg = threadIdx.x >> 5;
    const int row0 = blockIdx.x << 6;
    const int K4 = K >> 2;

    const float4* Av = (const float4*)A;
    float4* AsV = (float4*)As;
    // Stage A tile: 64 rows x K floats = 16*K float4s, coalesced.
    for (int idx = threadIdx.x; idx < 16 * K; idx += 256) {
        int rr = idx / K4, kk4 = idx - rr * K4;
        int row = row0 + rr;
        float4 v = make_float4(0.f, 0.f, 0.f, 0.f);
        if (row < N) v = Av[(size_t)row * K4 + kk4];
        AsV[rr * K4 + kk4] = v;
    }
    __syncthreads();

    const float4* Wv = (const float4*)W;
    float4 acc[8];
#pragma unroll
    for (int i = 0; i < 8; i++) acc[i] = make_float4(0.f, 0.f, 0.f, 0.f);

    for (int k4 = 0; k4 < K4; k4++) {
        float4 a[8];
#pragma unroll
        for (int i = 0; i < 8; i++) a[i] = AsV[(rg * 8 + i) * K4 + k4];
#pragma unroll
        for (int kk = 0; kk < 4; kk++) {
            float4 w = Wv[((k4 << 2) + kk) * 32 + c];
#pragma unroll
            for (int i = 0; i < 8; i++) {
                float av = kk == 0 ? a[i].x : kk == 1 ? a[i].y : kk == 2 ? a[i].z : a[i].w;
                acc[i].x += av * w.x;
                acc[i].y += av * w.y;
                acc[i].z += av * w.z;
                acc[i].w += av * w.w;
            }
        }
    }

    float4* Cv = (float4*)C;
    float4 bv;
    if (EPI == 2) bv = ((const float4*)bias)[c];
#pragma unroll
    for (int i = 0; i < 8; i++) {
        int row = row0 + rg * 8 + i;
        if (row < N) {
            size_t o = ((size_t)row << 5) + c;
            if (EPI == 0) {
                Cv[o] = acc[i];
            } else {
                float4 cur = Cv[o];
                float4 v;
                v.x = cur.x + acc[i].x + bv.x;
                v.y = cur.y + acc[i].y + bv.y;
                v.z = cur.z + acc[i].z + bv.z;
                v.w = cur.w + acc[i].w + bv.w;
                v.x = v.x > 0.f ? v.x : 0.f;
                v.y = v.y > 0.f ? v.y : 0.f;
                v.z = v.z > 0.f ? v.z : 0.f;
                v.w = v.w > 0.f ? v.w : 0.f;
                Cv[o] = v;
            }
        }
    }
}

// el/er for H=4, D=32, feat row stride 128. One thread per (node, head).
__global__ __launch_bounds__(256) void eler_k(const float* __restrict__ feat,
                                              const float* __restrict__ al,
                                              const float* __restrict__ ar,
                                              float* __restrict__ el,
                                              float* __restrict__ er, int N) {
    int idx = blockIdx.x * blockDim.x + threadIdx.x;
    if (idx >= N * 4) return;
    int n = idx >> 2, h = idx & 3;
    const float* f = feat + ((size_t)n << 7) + (h << 5);
    const float* a = al + (h << 5);
    const float* b = ar + (h << 5);
    float sl = 0.f, sr = 0.f;
#pragma unroll
    for (int d = 0; d < 32; d++) {
        float v = f[d];
        sl += v * a[d];
        sr += v * b[d];
    }
    el[idx] = sl;
    er[idx] = sr;
}

// ---------------- CSR build (dst-sorted) ----------------
__global__ __launch_bounds__(256) void count_k(const int* __restrict__ dst,
                                               int* __restrict__ deg, int E) {
    int e = blockIdx.x * 256 + threadIdx.x;
    if (e < E) atomicAdd(&deg[dst[e]], 1);
}

__global__ __launch_bounds__(256) void scan1_k(const int* __restrict__ deg,
                                               int* __restrict__ row_ptr,
                                               int* __restrict__ bsum, int N) {
    __shared__ int tmp[256];
    int i = blockIdx.x * 256 + threadIdx.x;
    int v = (i < N) ? deg[i] : 0;
    tmp[threadIdx.x] = v;
    __syncthreads();
    for (int off = 1; off < 256; off <<= 1) {
        int t = (threadIdx.x >= off) ? tmp[threadIdx.x - off] : 0;
        __syncthreads();
        tmp[threadIdx.x] += t;
        __syncthreads();
    }
    if (i < N) row_ptr[i] = tmp[threadIdx.x] - v;  // exclusive
    if (threadIdx.x == 255) bsum[blockIdx.x] = tmp[255];
}

__global__ __launch_bounds__(256) void scan2_k(int* __restrict__ bsum, int nb) {
    __shared__ int tmp[256];
    int v = (threadIdx.x < nb) ? bsum[threadIdx.x] : 0;
    tmp[threadIdx.x] = v;
    __syncthreads();
    for (int off = 1; off < 256; off <<= 1) {
        int t = (threadIdx.x >= off) ? tmp[threadIdx.x - off] : 0;
        __syncthreads();
        tmp[threadIdx.x] += t;
        __syncthreads();
    }
    if (threadIdx.x < nb) bsum[threadIdx.x] = tmp[threadIdx.x] - v;  // exclusive
}

__global__ __launch_bounds__(256) void scan3_k(int* __restrict__ row_ptr,
                                               const int* __restrict__ bsum,
                                               int N, int E) {
    int i = blockIdx.x * 256 + threadIdx.x;
    if (i < N) row_ptr[i] += bsum[i >> 8];
    if (i == 0) row_ptr[N] = E;
}

__global__ __launch_bounds__(256) void fill_k(const int* __restrict__ src,
                                              const int* __restrict__ dst,
                                              const int* __restrict__ row_ptr,
                                              int* __restrict__ cursor,
                                              int* __restrict__ csr_src, int E) {
    int e = blockIdx.x * 256 + threadIdx.x;
    if (e >= E) return;
    int d = dst[e];
    int pos = row_ptr[d] + atomicAdd(&cursor[d], 1);
    csr_src[pos] = src[e];
}

// ---------------- Pull aggregation (H=4, D=32) ----------------
// One wave (64 lanes) per dst node; lane l -> cols 2l,2l+1 (float2), head l>>4.
// 2-edge manual unroll for MLP. Fuses softmax denominator; BR fuses bias+relu.
template <bool BR>
__global__ __launch_bounds__(256) void pull_agg_k(const int* __restrict__ row_ptr,
                                                  const int* __restrict__ csr_src,
                                                  const float* __restrict__ el,
                                                  const float* __restrict__ er,
                                                  const float* __restrict__ feat,
                                                  const float* __restrict__ bias,
                                                  float* __restrict__ outp, int N) {
    int n = (blockIdx.x << 2) + (threadIdx.x >> 6);
    if (n >= N) return;
    int l = threadIdx.x & 63;
    int h = l >> 4;
    float erd = er[(n << 2) + h];
    const float2* feat2 = (const float2*)feat;
    int beg = row_ptr[n], end = row_ptr[n + 1];
    float ax = 0.f, ay = 0.f, den = 0.f;
    int p = beg;
    for (; p + 2 <= end; p += 2) {
        int s0 = csr_src[p];
        int s1 = csr_src[p + 1];
        float x0 = el[(s0 << 2) + h] + erd;
        float x1 = el[(s1 << 2) + h] + erd;
        float2 f0 = feat2[((size_t)s0 << 6) + l];
        float2 f1 = feat2[((size_t)s1 << 6) + l];
        x0 = x0 > 0.f ? x0 : NEG * x0;
        x1 = x1 > 0.f ? x1 : NEG * x1;
        float w0 = __expf(x0);
        float w1 = __expf(x1);
        den += w0 + w1;
        ax += w0 * f0.x + w1 * f1.x;
        ay += w0 * f0.y + w1 * f1.y;
    }
    if (p < end) {
        int s0 = csr_src[p];
        float x0 = el[(s0 << 2) + h] + erd;
        float2 f0 = feat2[((size_t)s0 << 6) + l];
        x0 = x0 > 0.f ? x0 : NEG * x0;
        float w0 = __expf(x0);
        den += w0;
        ax += w0 * f0.x;
        ay += w0 * f0.y;
    }
    float inv = 1.f / den;  // den >= 1 edge (self-loops)
    float2 v;
    v.x = ax * inv;
    v.y = ay * inv;
    if (BR) {
        float2 b = ((const float2*)bias)[l];
        v.x += b.x;
        v.y += b.y;
        v.x = v.x > 0.f ? v.x : 0.f;
        v.y = v.y > 0.f ? v.y : 0.f;
    }
    ((float2*)outp)[((size_t)n << 6) + l] = v;
}

// Layer 3: feat3 = h3 @ W3 (128 -> 6), per node.
__global__ __launch_bounds__(256) void feat3_k(const float* __restrict__ h3,
                                               const float* __restrict__ W3,
                                               float* __restrict__ feat3, int N) {
    int n = blockIdx.x * blockDim.x + threadIdx.x;
    if (n >= N) return;
    const float4* a = (const float4*)(h3 + ((size_t)n << 7));
    float f[6];
#pragma unroll
    for (int h = 0; h < 6; h++) f[h] = 0.f;
    for (int k4 = 0; k4 < 32; k4++) {
        float4 v = a[k4];
        int k = k4 << 2;
#pragma unroll
        for (int h = 0; h < 6; h++) {
            f[h] += v.x * W3[(k + 0) * 6 + h] + v.y * W3[(k + 1) * 6 + h] +
                    v.z * W3[(k + 2) * 6 + h] + v.w * W3[(k + 3) * 6 + h];
        }
    }
#pragma unroll
    for (int h = 0; h < 6; h++) feat3[n * 6 + h] = f[h];
}

// Layer 3 pull, one thread per (node, head). D=1:
// el[s,h] = feat3[s,h]*al3[h], er[d,h] = feat3[d,h]*ar3[h].
__global__ __launch_bounds__(256) void pull6_k(const int* __restrict__ row_ptr,
                                               const int* __restrict__ csr_src,
                                               const float* __restrict__ feat3,
                                               const float* __restrict__ al3,
                                               const float* __restrict__ ar3,
                                               float* __restrict__ rst3, int N) {
    int idx = blockIdx.x * blockDim.x + threadIdx.x;
    if (idx >= N * 6) return;
    int n = idx / 6, h = idx - n * 6;
    float a3 = al3[h], r3 = ar3[h];
    float fdr = feat3[idx] * r3;
    int beg = row_ptr[n], end = row_ptr[n + 1];
    float acc = 0.f, den = 0.f;
    int p = beg;
    for (; p + 2 <= end; p += 2) {
        int s0 = csr_src[p], s1 = csr_src[p + 1];
        float f0 = feat3[s0 * 6 + h];
        float f1 = feat3[s1 * 6 + h];
        float x0 = f0 * a3 + fdr;
        float x1 = f1 * a3 + fdr;
        x0 = x0 > 0.f ? x0 : NEG * x0;
        x1 = x1 > 0.f ? x1 : NEG * x1;
        float w0 = __expf(x0), w1 = __expf(x1);
        den += w0 + w1;
        acc += w0 * f0 + w1 * f1;
    }
    if (p < end) {
        int s0 = csr_src[p];
        float f0 = feat3[s0 * 6 + h];
        float x0 = f0 * a3 + fdr;
        x0 = x0 > 0.f ? x0 : NEG * x0;
        float w0 = __expf(x0);
        den += w0;
        acc += w0 * f0;
    }
    rst3[idx] = acc / den;
}

// Final: rst3 + h3@resW3 + b3, mean over 6 heads -> out[n].
__global__ __launch_bounds__(256) void final_k(const float* __restrict__ rst3,
                                               const float* __restrict__ h3,
                                               const float* __restrict__ resW3,
                                               const float* __restrict__ b3,
                                               float* __restrict__ out, int N) {
    int n = blockIdx.x * blockDim.x + threadIdx.x;
    if (n >= N) return;
    float r[6];
#pragma unroll
    for (int h = 0; h < 6; h++) r[h] = rst3[n * 6 + h] + b3[h];
    const float4* a = (const float4*)(h3 + ((size_t)n << 7));
    for (int k4 = 0; k4 < 32; k4++) {
        float4 v = a[k4];
        int k = k4 << 2;
#pragma unroll
        for (int h = 0; h < 6; h++)
            r[h] += v.x * resW3[(k + 0) * 6 + h] + v.y * resW3[(k + 1) * 6 + h] +
                    v.z * resW3[(k + 2) * 6 + h] + v.w * resW3[(k + 3) * 6 + h];
    }
    float m = 0.f;
#pragma unroll
    for (int h = 0; h < 6; h++) m += r[h];
    out[n] = m * (1.f / 6.f);
}

extern "C" void kernel_launch(void* const* d_in, const int* in_sizes, int n_in,
                              void* d_out, int out_size, void* d_ws, size_t ws_size,
                              hipStream_t stream) {
    const float* x = (const float*)d_in[0];
    const int* src = (const int*)d_in[1];
    const int* dst = (const int*)d_in[2];
    const float* W1 = (const float*)d_in[3];
    const float* al1 = (const float*)d_in[4];
    const float* ar1 = (const float*)d_in[5];
    const float* b1 = (const float*)d_in[6];
    const float* W2 = (const float*)d_in[7];
    const float* al2 = (const float*)d_in[8];
    const float* ar2 = (const float*)d_in[9];
    const float* b2 = (const float*)d_in[10];
    const float* resW2 = (const float*)d_in[11];
    const float* W3 = (const float*)d_in[12];
    const float* al3 = (const float*)d_in[13];
    const float* ar3 = (const float*)d_in[14];
    const float* b3 = (const float*)d_in[15];
    const float* resW3 = (const float*)d_in[16];
    float* out = (float*)d_out;

    const int N = in_sizes[0] / 64;
    const int E = in_sizes[1];

    // ---- workspace layout ----
    float* ws = (float*)d_ws;
    float* feat = ws;                        // N*128
    float* h2 = feat + (size_t)N * 128;      // N*128
    float* h3 = h2 + (size_t)N * 128;        // N*128
    float* el = h3 + (size_t)N * 128;        // N*4  (layer 1/2)
    float* er = el + (size_t)N * 4;          // N*4
    float* feat3 = el;                       // N*6 aliases el/er (free in layer 3)
    float* rst3 = er + (size_t)N * 4;        // N*6
    int* ip = (int*)(rst3 + (size_t)N * 6);
    int* deg = ip;                           // N
    int* cursor = deg + N;                   // N   (memset with deg)
    int* row_ptr = cursor + N;               // N+1
    int* bsum = row_ptr + N + 1;             // 256
    int* csr_src = bsum + 256;               // E

    const int gE = (E + 255) / 256;
    const int gN = (N + 255) / 256;
    const int gN64 = (N + 63) / 64;
    const int gNH = (N * 4 + 255) / 256;
    const int gN6 = (N * 6 + 255) / 256;
    const int gNw = (N + 3) / 4;  // wave-per-node blocks
    const int nb = gN;            // scan blocks (N/256 <= 256)

    // ---- build dst-CSR (shared by all 3 layers) ----
    hipMemsetAsync(deg, 0, sizeof(int) * 2 * N, stream);
    count_k<<<gE, 256, 0, stream>>>(dst, deg, E);
    scan1_k<<<nb, 256, 0, stream>>>(deg, row_ptr, bsum, N);
    scan2_k<<<1, 256, 0, stream>>>(bsum, nb);
    scan3_k<<<gN, 256, 0, stream>>>(row_ptr, bsum, N, E);
    fill_k<<<gE, 256, 0, stream>>>(src, dst, row_ptr, cursor, csr_src, E);

    // ---- Layer 1: 64 -> (4,32), relu, no residual ----
    gemm128_k<64, 0><<<gN64, 256, 0, stream>>>(x, W1, nullptr, feat, N);
    eler_k<<<gNH, 256, 0, stream>>>(feat, al1, ar1, el, er, N);
    pull_agg_k<true><<<gNw, 256, 0, stream>>>(row_ptr, csr_src, el, er, feat, b1, h2, N);

    // ---- Layer 2: 128 -> (4,32), relu, residual ----
    gemm128_k<128, 0><<<gN64, 256, 0, stream>>>(h2, W2, nullptr, feat, N);
    eler_k<<<gNH, 256, 0, stream>>>(feat, al2, ar2, el, er, N);
    pull_agg_k<false><<<gNw, 256, 0, stream>>>(row_ptr, csr_src, el, er, feat, nullptr, h3, N);
    // h3 = relu(h3 + h2@resW2 + b2)
    gemm128_k<128, 2><<<gN64, 256, 0, stream>>>(h2, resW2, b2, h3, N);

    // ---- Layer 3: 128 -> (6,1), no act, residual, mean over heads ----
    feat3_k<<<gN, 256, 0, stream>>>(h3, W3, feat3, N);
    pull6_k<<<gN6, 256, 0, stream>>>(row_ptr, csr_src, feat3, al3, ar3, rst3, N);
    final_k<<<gN, 256, 0, stream>>>(rst3, h3, resW3, b3, out, N);
}

// Round 4
// 415.547 us; speedup vs baseline: 29.1433x; 1.1046x over previous
//
#include <hip/hip_runtime.h>

#define NEG 0.2f

// ---------------- GEMM: C[N x 128] = A[N x K] @ W[K x 128] ----------------
// Block 256 threads -> 64 rows x 128 cols. Thread: rows rg*8..rg*8+7
// (rg = tid>>5), cols 4c..4c+3 (c = tid&31). A tile in LDS (float4 reads),
// W streamed as float4 (L2-hot, reused by all blocks).
// EPI 0: C = acc.  EPI 2: C = relu(C + acc + bias[j]) (residual fused).
// EL: also emit el/er = (C * al/ar).sum over D=32 per head (head = col>>5;
//     al flat index == col index, so each thread dots acc against al4/ar4 and
//     8 lanes (same row, same head) shfl-reduce).
template <int K, int EPI, bool EL>
__global__ __launch_bounds__(256) void gemm128_k(const float* __restrict__ A,
                                                 const float* __restrict__ W,
                                                 const float* __restrict__ bias,
                                                 const float* __restrict__ al,
                                                 const float* __restrict__ ar,
                                                 float* __restrict__ C,
                                                 float* __restrict__ el,
                                                 float* __restrict__ er, int N) {
    __shared__ float As[64 * K];
    const int c = threadIdx.x & 31;
    const int rg = threadIdx.x >> 5;
    const int row0 = blockIdx.x << 6;
    const int K4 = K >> 2;

    const float4* Av = (const float4*)A;
    float4* AsV = (float4*)As;
    for (int idx = threadIdx.x; idx < 16 * K; idx += 256) {
        int rr = idx / K4, kk4 = idx - rr * K4;
        int row = row0 + rr;
        float4 v = make_float4(0.f, 0.f, 0.f, 0.f);
        if (row < N) v = Av[(size_t)row * K4 + kk4];
        AsV[rr * K4 + kk4] = v;
    }
    __syncthreads();

    const float4* Wv = (const float4*)W;
    float4 acc[8];
#pragma unroll
    for (int i = 0; i < 8; i++) acc[i] = make_float4(0.f, 0.f, 0.f, 0.f);

    for (int k4 = 0; k4 < K4; k4++) {
        float4 a[8];
#pragma unroll
        for (int i = 0; i < 8; i++) a[i] = AsV[(rg * 8 + i) * K4 + k4];
#pragma unroll
        for (int kk = 0; kk < 4; kk++) {
            float4 w = Wv[((k4 << 2) + kk) * 32 + c];
#pragma unroll
            for (int i = 0; i < 8; i++) {
                float av = kk == 0 ? a[i].x : kk == 1 ? a[i].y : kk == 2 ? a[i].z : a[i].w;
                acc[i].x += av * w.x;
                acc[i].y += av * w.y;
                acc[i].z += av * w.z;
                acc[i].w += av * w.w;
            }
        }
    }

    float4* Cv = (float4*)C;
    float4 bv;
    if (EPI == 2) bv = ((const float4*)bias)[c];
#pragma unroll
    for (int i = 0; i < 8; i++) {
        int row = row0 + rg * 8 + i;
        if (row < N) {
            size_t o = ((size_t)row << 5) + c;
            if (EPI == 0) {
                Cv[o] = acc[i];
            } else {
                float4 cur = Cv[o];
                float4 v;
                v.x = cur.x + acc[i].x + bv.x;
                v.y = cur.y + acc[i].y + bv.y;
                v.z = cur.z + acc[i].z + bv.z;
                v.w = cur.w + acc[i].w + bv.w;
                v.x = v.x > 0.f ? v.x : 0.f;
                v.y = v.y > 0.f ? v.y : 0.f;
                v.z = v.z > 0.f ? v.z : 0.f;
                v.w = v.w > 0.f ? v.w : 0.f;
                Cv[o] = v;
            }
        }
    }

    if (EL) {
        float4 alv = ((const float4*)al)[c];
        float4 arv = ((const float4*)ar)[c];
        float pel[8], per_[8];
#pragma unroll
        for (int i = 0; i < 8; i++) {
            pel[i] = acc[i].x * alv.x + acc[i].y * alv.y + acc[i].z * alv.z + acc[i].w * alv.w;
            per_[i] = acc[i].x * arv.x + acc[i].y * arv.y + acc[i].z * arv.z + acc[i].w * arv.w;
        }
#pragma unroll
        for (int m = 1; m < 8; m <<= 1) {
#pragma unroll
            for (int i = 0; i < 8; i++) {
                pel[i] += __shfl_xor(pel[i], m);
                per_[i] += __shfl_xor(per_[i], m);
            }
        }
        if ((c & 7) == 0) {
            int h = c >> 3;
#pragma unroll
            for (int i = 0; i < 8; i++) {
                int row = row0 + rg * 8 + i;
                if (row < N) {
                    el[(row << 2) + h] = pel[i];
                    er[(row << 2) + h] = per_[i];
                }
            }
        }
    }
}

// ---------------- CSR build (dst-sorted) ----------------
__global__ __launch_bounds__(256) void count_k(const int* __restrict__ dst,
                                               int* __restrict__ deg, int E) {
    int e = blockIdx.x * 256 + threadIdx.x;
    if (e < E) atomicAdd(&deg[dst[e]], 1);
}

__global__ __launch_bounds__(256) void scan1_k(const int* __restrict__ deg,
                                               int* __restrict__ row_ptr,
                                               int* __restrict__ bsum, int N) {
    __shared__ int tmp[256];
    int i = blockIdx.x * 256 + threadIdx.x;
    int v = (i < N) ? deg[i] : 0;
    tmp[threadIdx.x] = v;
    __syncthreads();
    for (int off = 1; off < 256; off <<= 1) {
        int t = (threadIdx.x >= off) ? tmp[threadIdx.x - off] : 0;
        __syncthreads();
        tmp[threadIdx.x] += t;
        __syncthreads();
    }
    if (i < N) row_ptr[i] = tmp[threadIdx.x] - v;  // exclusive
    if (threadIdx.x == 255) bsum[blockIdx.x] = tmp[255];
}

__global__ __launch_bounds__(256) void scan2_k(int* __restrict__ bsum, int nb) {
    __shared__ int tmp[256];
    int v = (threadIdx.x < nb) ? bsum[threadIdx.x] : 0;
    tmp[threadIdx.x] = v;
    __syncthreads();
    for (int off = 1; off < 256; off <<= 1) {
        int t = (threadIdx.x >= off) ? tmp[threadIdx.x - off] : 0;
        __syncthreads();
        tmp[threadIdx.x] += t;
        __syncthreads();
    }
    if (threadIdx.x < nb) bsum[threadIdx.x] = tmp[threadIdx.x] - v;  // exclusive
}

__global__ __launch_bounds__(256) void scan3_k(int* __restrict__ row_ptr,
                                               const int* __restrict__ bsum,
                                               int N, int E) {
    int i = blockIdx.x * 256 + threadIdx.x;
    if (i < N) row_ptr[i] += bsum[i >> 8];
    if (i == 0) row_ptr[N] = E;
}

__global__ __launch_bounds__(256) void fill_k(const int* __restrict__ src,
                                              const int* __restrict__ dst,
                                              const int* __restrict__ row_ptr,
                                              int* __restrict__ cursor,
                                              int* __restrict__ csr_src, int E) {
    int e = blockIdx.x * 256 + threadIdx.x;
    if (e >= E) return;
    int d = dst[e];
    int pos = row_ptr[d] + atomicAdd(&cursor[d], 1);
    csr_src[pos] = src[e];
}

// ---------------- Pull aggregation (H=4, D=32) ----------------
// One wave per dst node; lane l -> cols 2l,2l+1 (float2), head l>>4.
// 4-edge unroll, 32-bit unsigned offsets (saddr-form global loads),
// leaky via fmaxf. Fuses softmax denominator; BR fuses bias+relu.
template <bool BR>
__global__ __launch_bounds__(256) void pull_agg_k(const int* __restrict__ row_ptr,
                                                  const int* __restrict__ csr_src,
                                                  const float* __restrict__ el,
                                                  const float* __restrict__ er,
                                                  const float* __restrict__ feat,
                                                  const float* __restrict__ bias,
                                                  float* __restrict__ outp, int N) {
    int n = (blockIdx.x << 2) + (threadIdx.x >> 6);
    if (n >= N) return;
    unsigned l = threadIdx.x & 63;
    unsigned h = l >> 4;
    float erd = er[((unsigned)n << 2) + h];
    const float2* feat2 = (const float2*)feat;
    int beg = row_ptr[n], end = row_ptr[n + 1];
    float ax = 0.f, ay = 0.f, den = 0.f;
    int p = beg;
    for (; p + 4 <= end; p += 4) {
        int s0 = csr_src[p], s1 = csr_src[p + 1];
        int s2 = csr_src[p + 2], s3 = csr_src[p + 3];
        float e0 = el[((unsigned)s0 << 2) + h];
        float e1 = el[((unsigned)s1 << 2) + h];
        float e2 = el[((unsigned)s2 << 2) + h];
        float e3 = el[((unsigned)s3 << 2) + h];
        float2 f0 = feat2[((unsigned)s0 << 6) + l];
        float2 f1 = feat2[((unsigned)s1 << 6) + l];
        float2 f2 = feat2[((unsigned)s2 << 6) + l];
        float2 f3 = feat2[((unsigned)s3 << 6) + l];
        float x0 = e0 + erd, x1 = e1 + erd, x2 = e2 + erd, x3 = e3 + erd;
        x0 = fmaxf(x0, NEG * x0);
        x1 = fmaxf(x1, NEG * x1);
        x2 = fmaxf(x2, NEG * x2);
        x3 = fmaxf(x3, NEG * x3);
        float w0 = __expf(x0), w1 = __expf(x1), w2 = __expf(x2), w3 = __expf(x3);
        den += (w0 + w1) + (w2 + w3);
        ax = fmaf(w0, f0.x, ax);
        ay = fmaf(w0, f0.y, ay);
        ax = fmaf(w1, f1.x, ax);
        ay = fmaf(w1, f1.y, ay);
        ax = fmaf(w2, f2.x, ax);
        ay = fmaf(w2, f2.y, ay);
        ax = fmaf(w3, f3.x, ax);
        ay = fmaf(w3, f3.y, ay);
    }
    for (; p < end; p++) {
        int s0 = csr_src[p];
        float e0 = el[((unsigned)s0 << 2) + h];
        float2 f0 = feat2[((unsigned)s0 << 6) + l];
        float x0 = e0 + erd;
        x0 = fmaxf(x0, NEG * x0);
        float w0 = __expf(x0);
        den += w0;
        ax = fmaf(w0, f0.x, ax);
        ay = fmaf(w0, f0.y, ay);
    }
    float inv = 1.f / den;  // den >= 1 edge (self-loops)
    float2 v;
    v.x = ax * inv;
    v.y = ay * inv;
    if (BR) {
        float2 b = ((const float2*)bias)[l];
        v.x += b.x;
        v.y += b.y;
        v.x = v.x > 0.f ? v.x : 0.f;
        v.y = v.y > 0.f ? v.y : 0.f;
    }
    ((float2*)outp)[((size_t)n << 6) + l] = v;
}

// Layer 3: feat3 = h3 @ W3 (128 -> 6), per node.
__global__ __launch_bounds__(256) void feat3_k(const float* __restrict__ h3,
                                               const float* __restrict__ W3,
                                               float* __restrict__ feat3, int N) {
    int n = blockIdx.x * blockDim.x + threadIdx.x;
    if (n >= N) return;
    const float4* a = (const float4*)(h3 + ((size_t)n << 7));
    float f[6];
#pragma unroll
    for (int h = 0; h < 6; h++) f[h] = 0.f;
    for (int k4 = 0; k4 < 32; k4++) {
        float4 v = a[k4];
        int k = k4 << 2;
#pragma unroll
        for (int h = 0; h < 6; h++) {
            f[h] += v.x * W3[(k + 0) * 6 + h] + v.y * W3[(k + 1) * 6 + h] +
                    v.z * W3[(k + 2) * 6 + h] + v.w * W3[(k + 3) * 6 + h];
        }
    }
#pragma unroll
    for (int h = 0; h < 6; h++) feat3[n * 6 + h] = f[h];
}

// Layer 3 pull, one thread per (node, head). D=1:
// el[s,h] = feat3[s,h]*al3[h], er[d,h] = feat3[d,h]*ar3[h].
__global__ __launch_bounds__(256) void pull6_k(const int* __restrict__ row_ptr,
                                               const int* __restrict__ csr_src,
                                               const float* __restrict__ feat3,
                                               const float* __restrict__ al3,
                                               const float* __restrict__ ar3,
                                               float* __restrict__ rst3, int N) {
    int idx = blockIdx.x * blockDim.x + threadIdx.x;
    if (idx >= N * 6) return;
    int n = idx / 6, h = idx - n * 6;
    float a3 = al3[h], r3 = ar3[h];
    float fdr = feat3[idx] * r3;
    int beg = row_ptr[n], end = row_ptr[n + 1];
    float acc = 0.f, den = 0.f;
    int p = beg;
    for (; p + 2 <= end; p += 2) {
        int s0 = csr_src[p], s1 = csr_src[p + 1];
        float f0 = feat3[(unsigned)s0 * 6 + h];
        float f1 = feat3[(unsigned)s1 * 6 + h];
        float x0 = fmaf(f0, a3, fdr);
        float x1 = fmaf(f1, a3, fdr);
        x0 = fmaxf(x0, NEG * x0);
        x1 = fmaxf(x1, NEG * x1);
        float w0 = __expf(x0), w1 = __expf(x1);
        den += w0 + w1;
        acc = fmaf(w0, f0, acc);
        acc = fmaf(w1, f1, acc);
    }
    if (p < end) {
        int s0 = csr_src[p];
        float f0 = feat3[(unsigned)s0 * 6 + h];
        float x0 = fmaf(f0, a3, fdr);
        x0 = fmaxf(x0, NEG * x0);
        float w0 = __expf(x0);
        den += w0;
        acc = fmaf(w0, f0, acc);
    }
    rst3[idx] = acc / den;
}

// Final: rst3 + h3@resW3 + b3, mean over 6 heads -> out[n].
__global__ __launch_bounds__(256) void final_k(const float* __restrict__ rst3,
                                               const float* __restrict__ h3,
                                               const float* __restrict__ resW3,
                                               const float* __restrict__ b3,
                                               float* __restrict__ out, int N) {
    int n = blockIdx.x * blockDim.x + threadIdx.x;
    if (n >= N) return;
    float r[6];
#pragma unroll
    for (int h = 0; h < 6; h++) r[h] = rst3[n * 6 + h] + b3[h];
    const float4* a = (const float4*)(h3 + ((size_t)n << 7));
    for (int k4 = 0; k4 < 32; k4++) {
        float4 v = a[k4];
        int k = k4 << 2;
#pragma unroll
        for (int h = 0; h < 6; h++)
            r[h] += v.x * resW3[(k + 0) * 6 + h] + v.y * resW3[(k + 1) * 6 + h] +
                    v.z * resW3[(k + 2) * 6 + h] + v.w * resW3[(k + 3) * 6 + h];
    }
    float m = 0.f;
#pragma unroll
    for (int h = 0; h < 6; h++) m += r[h];
    out[n] = m * (1.f / 6.f);
}

extern "C" void kernel_launch(void* const* d_in, const int* in_sizes, int n_in,
                              void* d_out, int out_size, void* d_ws, size_t ws_size,
                              hipStream_t stream) {
    const float* x = (const float*)d_in[0];
    const int* src = (const int*)d_in[1];
    const int* dst = (const int*)d_in[2];
    const float* W1 = (const float*)d_in[3];
    const float* al1 = (const float*)d_in[4];
    const float* ar1 = (const float*)d_in[5];
    const float* b1 = (const float*)d_in[6];
    const float* W2 = (const float*)d_in[7];
    const float* al2 = (const float*)d_in[8];
    const float* ar2 = (const float*)d_in[9];
    const float* b2 = (const float*)d_in[10];
    const float* resW2 = (const float*)d_in[11];
    const float* W3 = (const float*)d_in[12];
    const float* al3 = (const float*)d_in[13];
    const float* ar3 = (const float*)d_in[14];
    const float* b3 = (const float*)d_in[15];
    const float* resW3 = (const float*)d_in[16];
    float* out = (float*)d_out;

    const int N = in_sizes[0] / 64;
    const int E = in_sizes[1];

    // ---- workspace layout ----
    float* ws = (float*)d_ws;
    float* feat = ws;                        // N*128
    float* h2 = feat + (size_t)N * 128;      // N*128
    float* h3 = h2 + (size_t)N * 128;        // N*128
    float* el = h3 + (size_t)N * 128;        // N*4  (layer 1/2)
    float* er = el + (size_t)N * 4;          // N*4
    float* feat3 = el;                       // N*6 aliases el/er (free in layer 3)
    float* rst3 = er + (size_t)N * 4;        // N*6
    int* ip = (int*)(rst3 + (size_t)N * 6);
    int* deg = ip;                           // N
    int* cursor = deg + N;                   // N   (memset with deg)
    int* row_ptr = cursor + N;               // N+1
    int* bsum = row_ptr + N + 1;             // 256
    int* csr_src = bsum + 256;               // E

    const int gE = (E + 255) / 256;
    const int gN = (N + 255) / 256;
    const int gN64 = (N + 63) / 64;
    const int gN6 = (N * 6 + 255) / 256;
    const int gNw = (N + 3) / 4;  // wave-per-node blocks
    const int nb = gN;            // scan blocks (N/256 <= 256)

    // ---- build dst-CSR (shared by all 3 layers) ----
    hipMemsetAsync(deg, 0, sizeof(int) * 2 * N, stream);
    count_k<<<gE, 256, 0, stream>>>(dst, deg, E);
    scan1_k<<<nb, 256, 0, stream>>>(deg, row_ptr, bsum, N);
    scan2_k<<<1, 256, 0, stream>>>(bsum, nb);
    scan3_k<<<gN, 256, 0, stream>>>(row_ptr, bsum, N, E);
    fill_k<<<gE, 256, 0, stream>>>(src, dst, row_ptr, cursor, csr_src, E);

    // ---- Layer 1: 64 -> (4,32), relu, no residual ----
    gemm128_k<64, 0, true><<<gN64, 256, 0, stream>>>(x, W1, nullptr, al1, ar1,
                                                     feat, el, er, N);
    pull_agg_k<true><<<gNw, 256, 0, stream>>>(row_ptr, csr_src, el, er, feat, b1, h2, N);

    // ---- Layer 2: 128 -> (4,32), relu, residual ----
    gemm128_k<128, 0, true><<<gN64, 256, 0, stream>>>(h2, W2, nullptr, al2, ar2,
                                                      feat, el, er, N);
    pull_agg_k<false><<<gNw, 256, 0, stream>>>(row_ptr, csr_src, el, er, feat, nullptr, h3, N);
    // h3 = relu(h3 + h2@resW2 + b2)
    gemm128_k<128, 2, false><<<gN64, 256, 0, stream>>>(h2, resW2, b2, nullptr, nullptr,
                                                       h3, nullptr, nullptr, N);

    // ---- Layer 3: 128 -> (6,1), no act, residual, mean over heads ----
    feat3_k<<<gN, 256, 0, stream>>>(h3, W3, feat3, N);
    pull6_k<<<gN6, 256, 0, stream>>>(row_ptr, csr_src, feat3, al3, ar3, rst3, N);
    final_k<<<gN, 256, 0, stream>>>(rst3, h3, resW3, b3, out, N);
}

// Round 5
// 368.656 us; speedup vs baseline: 32.8502x; 1.1272x over previous
//
#include <hip/hip_runtime.h>
#include <hip/hip_fp16.h>

#define NEG 0.2f

// ------- GEMM + el/er epilogue, fp16 feat output (layers 1 & 2) -------
// Block 256 threads -> 64 rows x 128 cols. Thread: rows rg*8..rg*8+7
// (rg = tid>>5), cols 4c..4c+3 (c = tid&31). A tile in LDS (float4 reads),
// W streamed as float4 (L2-hot). Output feat is fp16 (pull_agg is the only
// consumer); el/er = per-head dot of the row against al/ar (8-lane shfl
// reduce; head = col>>5 so al flat index == col index).
template <int K>
__global__ __launch_bounds__(256) void gemm_el_k(const float* __restrict__ A,
                                                 const float* __restrict__ W,
                                                 const float* __restrict__ al,
                                                 const float* __restrict__ ar,
                                                 __half* __restrict__ feat_h,
                                                 float* __restrict__ el,
                                                 float* __restrict__ er, int N) {
    __shared__ float As[64 * K];
    const int c = threadIdx.x & 31;
    const int rg = threadIdx.x >> 5;
    const int row0 = blockIdx.x << 6;
    const int K4 = K >> 2;

    const float4* Av = (const float4*)A;
    float4* AsV = (float4*)As;
    for (int idx = threadIdx.x; idx < 16 * K; idx += 256) {
        int rr = idx / K4, kk4 = idx - rr * K4;
        int row = row0 + rr;
        float4 v = make_float4(0.f, 0.f, 0.f, 0.f);
        if (row < N) v = Av[(size_t)row * K4 + kk4];
        AsV[rr * K4 + kk4] = v;
    }
    __syncthreads();

    const float4* Wv = (const float4*)W;
    float4 acc[8];
#pragma unroll
    for (int i = 0; i < 8; i++) acc[i] = make_float4(0.f, 0.f, 0.f, 0.f);

    for (int k4 = 0; k4 < K4; k4++) {
        float4 a[8];
#pragma unroll
        for (int i = 0; i < 8; i++) a[i] = AsV[(rg * 8 + i) * K4 + k4];
#pragma unroll
        for (int kk = 0; kk < 4; kk++) {
            float4 w = Wv[((k4 << 2) + kk) * 32 + c];
#pragma unroll
            for (int i = 0; i < 8; i++) {
                float av = kk == 0 ? a[i].x : kk == 1 ? a[i].y : kk == 2 ? a[i].z : a[i].w;
                acc[i].x += av * w.x;
                acc[i].y += av * w.y;
                acc[i].z += av * w.z;
                acc[i].w += av * w.w;
            }
        }
    }

    __half2* Fh2 = (__half2*)feat_h;
#pragma unroll
    for (int i = 0; i < 8; i++) {
        int row = row0 + rg * 8 + i;
        if (row < N) {
            size_t o = ((size_t)row << 6) + (c << 1);
            Fh2[o] = __floats2half2_rn(acc[i].x, acc[i].y);
            Fh2[o + 1] = __floats2half2_rn(acc[i].z, acc[i].w);
        }
    }

    float4 alv = ((const float4*)al)[c];
    float4 arv = ((const float4*)ar)[c];
    float pel[8], per_[8];
#pragma unroll
    for (int i = 0; i < 8; i++) {
        pel[i] = acc[i].x * alv.x + acc[i].y * alv.y + acc[i].z * alv.z + acc[i].w * alv.w;
        per_[i] = acc[i].x * arv.x + acc[i].y * arv.y + acc[i].z * arv.z + acc[i].w * arv.w;
    }
#pragma unroll
    for (int m = 1; m < 8; m <<= 1) {
#pragma unroll
        for (int i = 0; i < 8; i++) {
            pel[i] += __shfl_xor(pel[i], m);
            per_[i] += __shfl_xor(per_[i], m);
        }
    }
    if ((c & 7) == 0) {
        int h = c >> 3;
#pragma unroll
        for (int i = 0; i < 8; i++) {
            int row = row0 + rg * 8 + i;
            if (row < N) {
                el[(row << 2) + h] = pel[i];
                er[(row << 2) + h] = per_[i];
            }
        }
    }
}

// ------- Residual GEMM: C = relu(C + A@W + bias), fp32 (layer 2) -------
template <int K>
__global__ __launch_bounds__(256) void gemm_res_k(const float* __restrict__ A,
                                                  const float* __restrict__ W,
                                                  const float* __restrict__ bias,
                                                  float* __restrict__ C, int N) {
    __shared__ float As[64 * K];
    const int c = threadIdx.x & 31;
    const int rg = threadIdx.x >> 5;
    const int row0 = blockIdx.x << 6;
    const int K4 = K >> 2;

    const float4* Av = (const float4*)A;
    float4* AsV = (float4*)As;
    for (int idx = threadIdx.x; idx < 16 * K; idx += 256) {
        int rr = idx / K4, kk4 = idx - rr * K4;
        int row = row0 + rr;
        float4 v = make_float4(0.f, 0.f, 0.f, 0.f);
        if (row < N) v = Av[(size_t)row * K4 + kk4];
        AsV[rr * K4 + kk4] = v;
    }
    __syncthreads();

    const float4* Wv = (const float4*)W;
    float4 acc[8];
#pragma unroll
    for (int i = 0; i < 8; i++) acc[i] = make_float4(0.f, 0.f, 0.f, 0.f);

    for (int k4 = 0; k4 < K4; k4++) {
        float4 a[8];
#pragma unroll
        for (int i = 0; i < 8; i++) a[i] = AsV[(rg * 8 + i) * K4 + k4];
#pragma unroll
        for (int kk = 0; kk < 4; kk++) {
            float4 w = Wv[((k4 << 2) + kk) * 32 + c];
#pragma unroll
            for (int i = 0; i < 8; i++) {
                float av = kk == 0 ? a[i].x : kk == 1 ? a[i].y : kk == 2 ? a[i].z : a[i].w;
                acc[i].x += av * w.x;
                acc[i].y += av * w.y;
                acc[i].z += av * w.z;
                acc[i].w += av * w.w;
            }
        }
    }

    float4* Cv = (float4*)C;
    float4 bv = ((const float4*)bias)[c];
#pragma unroll
    for (int i = 0; i < 8; i++) {
        int row = row0 + rg * 8 + i;
        if (row < N) {
            size_t o = ((size_t)row << 5) + c;
            float4 cur = Cv[o];
            float4 v;
            v.x = fmaxf(cur.x + acc[i].x + bv.x, 0.f);
            v.y = fmaxf(cur.y + acc[i].y + bv.y, 0.f);
            v.z = fmaxf(cur.z + acc[i].z + bv.z, 0.f);
            v.w = fmaxf(cur.w + acc[i].w + bv.w, 0.f);
            Cv[o] = v;
        }
    }
}

// ---------------- CSR build (dst-sorted) ----------------
__global__ __launch_bounds__(256) void count_k(const int* __restrict__ dst,
                                               int* __restrict__ deg, int E) {
    int e = blockIdx.x * 256 + threadIdx.x;
    if (e < E) atomicAdd(&deg[dst[e]], 1);
}

__global__ __launch_bounds__(256) void scan1_k(const int* __restrict__ deg,
                                               int* __restrict__ row_ptr,
                                               int* __restrict__ bsum, int N) {
    __shared__ int tmp[256];
    int i = blockIdx.x * 256 + threadIdx.x;
    int v = (i < N) ? deg[i] : 0;
    tmp[threadIdx.x] = v;
    __syncthreads();
    for (int off = 1; off < 256; off <<= 1) {
        int t = (threadIdx.x >= off) ? tmp[threadIdx.x - off] : 0;
        __syncthreads();
        tmp[threadIdx.x] += t;
        __syncthreads();
    }
    if (i < N) row_ptr[i] = tmp[threadIdx.x] - v;  // exclusive
    if (threadIdx.x == 255) bsum[blockIdx.x] = tmp[255];
}

__global__ __launch_bounds__(256) void scan2_k(int* __restrict__ bsum, int nb) {
    __shared__ int tmp[256];
    int v = (threadIdx.x < nb) ? bsum[threadIdx.x] : 0;
    tmp[threadIdx.x] = v;
    __syncthreads();
    for (int off = 1; off < 256; off <<= 1) {
        int t = (threadIdx.x >= off) ? tmp[threadIdx.x - off] : 0;
        __syncthreads();
        tmp[threadIdx.x] += t;
        __syncthreads();
    }
    if (threadIdx.x < nb) bsum[threadIdx.x] = tmp[threadIdx.x] - v;  // exclusive
}

__global__ __launch_bounds__(256) void scan3_k(int* __restrict__ row_ptr,
                                               const int* __restrict__ bsum,
                                               int N, int E) {
    int i = blockIdx.x * 256 + threadIdx.x;
    if (i < N) row_ptr[i] += bsum[i >> 8];
    if (i == 0) row_ptr[N] = E;
}

__global__ __launch_bounds__(256) void fill_k(const int* __restrict__ src,
                                              const int* __restrict__ dst,
                                              const int* __restrict__ row_ptr,
                                              int* __restrict__ cursor,
                                              int* __restrict__ csr_src, int E) {
    int e = blockIdx.x * 256 + threadIdx.x;
    if (e >= E) return;
    int d = dst[e];
    int pos = row_ptr[d] + atomicAdd(&cursor[d], 1);
    csr_src[pos] = src[e];
}

// ---------------- Pull aggregation (H=4, D=32, fp16 feat) ----------------
// One wave per dst node; lane l -> cols 2l,2l+1 (half2 load), head l>>4.
// CSR walk scalarized (readfirstlane -> s_load). Fuses softmax denominator;
// BR fuses bias+relu. Output fp32.
template <bool BR>
__global__ __launch_bounds__(256) void pull_agg_k(const int* __restrict__ row_ptr,
                                                  const int* __restrict__ csr_src,
                                                  const float* __restrict__ el,
                                                  const float* __restrict__ er,
                                                  const __half* __restrict__ feat_h,
                                                  const float* __restrict__ bias,
                                                  float* __restrict__ outp, int N) {
    int n = (blockIdx.x << 2) + (threadIdx.x >> 6);
    if (n >= N) return;
    unsigned l = threadIdx.x & 63;
    unsigned h = l >> 4;
    float erd = er[((unsigned)n << 2) + h];
    const __half2* feat2 = (const __half2*)feat_h;
    int beg = __builtin_amdgcn_readfirstlane(row_ptr[n]);
    int end = __builtin_amdgcn_readfirstlane(row_ptr[n + 1]);
    float ax = 0.f, ay = 0.f, den = 0.f;
    int p = beg;
    for (; p + 4 <= end; p += 4) {
        int s0 = csr_src[p], s1 = csr_src[p + 1];
        int s2 = csr_src[p + 2], s3 = csr_src[p + 3];
        float e0 = el[((unsigned)s0 << 2) + h];
        float e1 = el[((unsigned)s1 << 2) + h];
        float e2 = el[((unsigned)s2 << 2) + h];
        float e3 = el[((unsigned)s3 << 2) + h];
        __half2 g0 = feat2[((unsigned)s0 << 6) + l];
        __half2 g1 = feat2[((unsigned)s1 << 6) + l];
        __half2 g2 = feat2[((unsigned)s2 << 6) + l];
        __half2 g3 = feat2[((unsigned)s3 << 6) + l];
        float x0 = e0 + erd, x1 = e1 + erd, x2 = e2 + erd, x3 = e3 + erd;
        x0 = fmaxf(x0, NEG * x0);
        x1 = fmaxf(x1, NEG * x1);
        x2 = fmaxf(x2, NEG * x2);
        x3 = fmaxf(x3, NEG * x3);
        float w0 = __expf(x0), w1 = __expf(x1), w2 = __expf(x2), w3 = __expf(x3);
        float2 f0 = __half22float2(g0), f1 = __half22float2(g1);
        float2 f2 = __half22float2(g2), f3 = __half22float2(g3);
        den += (w0 + w1) + (w2 + w3);
        ax = fmaf(w0, f0.x, ax);
        ay = fmaf(w0, f0.y, ay);
        ax = fmaf(w1, f1.x, ax);
        ay = fmaf(w1, f1.y, ay);
        ax = fmaf(w2, f2.x, ax);
        ay = fmaf(w2, f2.y, ay);
        ax = fmaf(w3, f3.x, ax);
        ay = fmaf(w3, f3.y, ay);
    }
    for (; p < end; p++) {
        int s0 = csr_src[p];
        float e0 = el[((unsigned)s0 << 2) + h];
        __half2 g0 = feat2[((unsigned)s0 << 6) + l];
        float x0 = e0 + erd;
        x0 = fmaxf(x0, NEG * x0);
        float w0 = __expf(x0);
        float2 f0 = __half22float2(g0);
        den += w0;
        ax = fmaf(w0, f0.x, ax);
        ay = fmaf(w0, f0.y, ay);
    }
    float inv = 1.f / den;  // den >= 1 edge (self-loops)
    float2 v;
    v.x = ax * inv;
    v.y = ay * inv;
    if (BR) {
        float2 b = ((const float2*)bias)[l];
        v.x = fmaxf(v.x + b.x, 0.f);
        v.y = fmaxf(v.y + b.y, 0.f);
    }
    ((float2*)outp)[((size_t)n << 6) + l] = v;
}

// Layer 3: feat3 = h3 @ W3 and res3 = h3 @ resW3 + b3 (128 -> 6), one pass.
__global__ __launch_bounds__(256) void feat3res_k(const float* __restrict__ h3,
                                                  const float* __restrict__ W3,
                                                  const float* __restrict__ resW3,
                                                  const float* __restrict__ b3,
                                                  float* __restrict__ feat3,
                                                  float* __restrict__ res3, int N) {
    int n = blockIdx.x * blockDim.x + threadIdx.x;
    if (n >= N) return;
    const float4* a = (const float4*)(h3 + ((size_t)n << 7));
    float f[6], r[6];
#pragma unroll
    for (int h = 0; h < 6; h++) {
        f[h] = 0.f;
        r[h] = b3[h];
    }
    for (int k4 = 0; k4 < 32; k4++) {
        float4 v = a[k4];
        int k = k4 << 2;
#pragma unroll
        for (int h = 0; h < 6; h++) {
            f[h] += v.x * W3[(k + 0) * 6 + h] + v.y * W3[(k + 1) * 6 + h] +
                    v.z * W3[(k + 2) * 6 + h] + v.w * W3[(k + 3) * 6 + h];
            r[h] += v.x * resW3[(k + 0) * 6 + h] + v.y * resW3[(k + 1) * 6 + h] +
                    v.z * resW3[(k + 2) * 6 + h] + v.w * resW3[(k + 3) * 6 + h];
        }
    }
#pragma unroll
    for (int h = 0; h < 6; h++) {
        feat3[n * 6 + h] = f[h];
        res3[n * 6 + h] = r[h];
    }
}

// Layer 3 pull, one thread per (node, head); adds res3. D=1:
// el[s,h] = feat3[s,h]*al3[h], er[d,h] = feat3[d,h]*ar3[h].
__global__ __launch_bounds__(256) void pull6_k(const int* __restrict__ row_ptr,
                                               const int* __restrict__ csr_src,
                                               const float* __restrict__ feat3,
                                               const float* __restrict__ al3,
                                               const float* __restrict__ ar3,
                                               const float* __restrict__ res3,
                                               float* __restrict__ rst3, int N) {
    int idx = blockIdx.x * blockDim.x + threadIdx.x;
    if (idx >= N * 6) return;
    int n = idx / 6, h = idx - n * 6;
    float a3 = al3[h], r3 = ar3[h];
    float fdr = feat3[idx] * r3;
    int beg = row_ptr[n], end = row_ptr[n + 1];
    float acc = 0.f, den = 0.f;
    int p = beg;
    for (; p + 2 <= end; p += 2) {
        int s0 = csr_src[p], s1 = csr_src[p + 1];
        float f0 = feat3[(unsigned)s0 * 6 + h];
        float f1 = feat3[(unsigned)s1 * 6 + h];
        float x0 = fmaf(f0, a3, fdr);
        float x1 = fmaf(f1, a3, fdr);
        x0 = fmaxf(x0, NEG * x0);
        x1 = fmaxf(x1, NEG * x1);
        float w0 = __expf(x0), w1 = __expf(x1);
        den += w0 + w1;
        acc = fmaf(w0, f0, acc);
        acc = fmaf(w1, f1, acc);
    }
    if (p < end) {
        int s0 = csr_src[p];
        float f0 = feat3[(unsigned)s0 * 6 + h];
        float x0 = fmaf(f0, a3, fdr);
        x0 = fmaxf(x0, NEG * x0);
        float w0 = __expf(x0);
        den += w0;
        acc = fmaf(w0, f0, acc);
    }
    rst3[idx] = acc / den + res3[idx];
}

// Final: mean over 6 heads -> out[n].
__global__ __launch_bounds__(256) void final_k(const float* __restrict__ rst3,
                                               float* __restrict__ out, int N) {
    int n = blockIdx.x * blockDim.x + threadIdx.x;
    if (n >= N) return;
    const float2* r2 = (const float2*)(rst3 + n * 6);
    float2 a = r2[0], b = r2[1], c = r2[2];
    out[n] = (a.x + a.y + b.x + b.y + c.x + c.y) * (1.f / 6.f);
}

extern "C" void kernel_launch(void* const* d_in, const int* in_sizes, int n_in,
                              void* d_out, int out_size, void* d_ws, size_t ws_size,
                              hipStream_t stream) {
    const float* x = (const float*)d_in[0];
    const int* src = (const int*)d_in[1];
    const int* dst = (const int*)d_in[2];
    const float* W1 = (const float*)d_in[3];
    const float* al1 = (const float*)d_in[4];
    const float* ar1 = (const float*)d_in[5];
    const float* W2 = (const float*)d_in[7];
    const float* al2 = (const float*)d_in[8];
    const float* ar2 = (const float*)d_in[9];
    const float* b1 = (const float*)d_in[6];
    const float* b2 = (const float*)d_in[10];
    const float* resW2 = (const float*)d_in[11];
    const float* W3 = (const float*)d_in[12];
    const float* al3 = (const float*)d_in[13];
    const float* ar3 = (const float*)d_in[14];
    const float* b3 = (const float*)d_in[15];
    const float* resW3 = (const float*)d_in[16];
    float* out = (float*)d_out;

    const int N = in_sizes[0] / 64;
    const int E = in_sizes[1];

    // ---- workspace layout ----
    float* ws = (float*)d_ws;
    __half* feat_h = (__half*)ws;            // N*128 halves == N*64 floats
    float* h2 = ws + (size_t)N * 64;         // N*128 f32
    float* h3 = h2 + (size_t)N * 128;        // N*128 f32
    float* el = h3 + (size_t)N * 128;        // N*4
    float* er = el + (size_t)N * 4;          // N*4
    float* feat3 = el;                       // N*6 aliases el/er (free in layer 3)
    float* res3 = er + (size_t)N * 4;        // N*6
    float* rst3 = res3 + (size_t)N * 6;      // N*6
    int* ip = (int*)(rst3 + (size_t)N * 6);
    int* deg = ip;                           // N
    int* cursor = deg + N;                   // N (memset with deg)
    int* row_ptr = cursor + N;               // N+1
    int* bsum = row_ptr + N + 1;             // 256
    int* csr_src = bsum + 256;               // E

    const int gE = (E + 255) / 256;
    const int gN = (N + 255) / 256;
    const int gN64 = (N + 63) / 64;
    const int gN6 = (N * 6 + 255) / 256;
    const int gNw = (N + 3) / 4;  // wave-per-node blocks
    const int nb = gN;            // scan blocks (N/256 <= 256)

    // ---- build dst-CSR (shared by all 3 layers) ----
    hipMemsetAsync(deg, 0, sizeof(int) * 2 * N, stream);
    count_k<<<gE, 256, 0, stream>>>(dst, deg, E);
    scan1_k<<<nb, 256, 0, stream>>>(deg, row_ptr, bsum, N);
    scan2_k<<<1, 256, 0, stream>>>(bsum, nb);
    scan3_k<<<gN, 256, 0, stream>>>(row_ptr, bsum, N, E);
    fill_k<<<gE, 256, 0, stream>>>(src, dst, row_ptr, cursor, csr_src, E);

    // ---- Layer 1: 64 -> (4,32), relu, no residual ----
    gemm_el_k<64><<<gN64, 256, 0, stream>>>(x, W1, al1, ar1, feat_h, el, er, N);
    pull_agg_k<true><<<gNw, 256, 0, stream>>>(row_ptr, csr_src, el, er, feat_h, b1, h2, N);

    // ---- Layer 2: 128 -> (4,32), relu, residual ----
    gemm_el_k<128><<<gN64, 256, 0, stream>>>(h2, W2, al2, ar2, feat_h, el, er, N);
    pull_agg_k<false><<<gNw, 256, 0, stream>>>(row_ptr, csr_src, el, er, feat_h, nullptr, h3, N);
    // h3 = relu(h3 + h2@resW2 + b2)
    gemm_res_k<128><<<gN64, 256, 0, stream>>>(h2, resW2, b2, h3, N);

    // ---- Layer 3: 128 -> (6,1), no act, residual, mean over heads ----
    feat3res_k<<<gN, 256, 0, stream>>>(h3, W3, resW3, b3, feat3, res3, N);
    pull6_k<<<gN6, 256, 0, stream>>>(row_ptr, csr_src, feat3, al3, ar3, res3, rst3, N);
    final_k<<<gN, 256, 0, stream>>>(rst3, out, N);
}

// Round 6
// 302.800 us; speedup vs baseline: 39.9948x; 1.2175x over previous
//
#include <hip/hip_runtime.h>
#include <hip/hip_fp16.h>

#define NEG 0.2f
// Bucketed CSR build: buckets of 128 dst nodes, fixed slab capacity per bucket.
// N=50000 -> NB=391 buckets; bucket edges ~ Poisson(2048)+128 = 2176 +/- 46;
// CAP=3200 is >20 sigma of headroom (clamped defensively regardless).
#define BUCKET_SHIFT 7
#define CAP 3200
#define PCHUNK 4096

// ------- GEMM + el/er epilogue, fp16 feat output (layers 1 & 2) -------
template <int K>
__global__ __launch_bounds__(256) void gemm_el_k(const float* __restrict__ A,
                                                 const float* __restrict__ W,
                                                 const float* __restrict__ al,
                                                 const float* __restrict__ ar,
                                                 __half* __restrict__ feat_h,
                                                 float* __restrict__ el,
                                                 float* __restrict__ er, int N) {
    __shared__ float As[64 * K];
    const int c = threadIdx.x & 31;
    const int rg = threadIdx.x >> 5;
    const int row0 = blockIdx.x << 6;
    const int K4 = K >> 2;

    const float4* Av = (const float4*)A;
    float4* AsV = (float4*)As;
    for (int idx = threadIdx.x; idx < 16 * K; idx += 256) {
        int rr = idx / K4, kk4 = idx - rr * K4;
        int row = row0 + rr;
        float4 v = make_float4(0.f, 0.f, 0.f, 0.f);
        if (row < N) v = Av[(size_t)row * K4 + kk4];
        AsV[rr * K4 + kk4] = v;
    }
    __syncthreads();

    const float4* Wv = (const float4*)W;
    float4 acc[8];
#pragma unroll
    for (int i = 0; i < 8; i++) acc[i] = make_float4(0.f, 0.f, 0.f, 0.f);

    for (int k4 = 0; k4 < K4; k4++) {
        float4 a[8];
#pragma unroll
        for (int i = 0; i < 8; i++) a[i] = AsV[(rg * 8 + i) * K4 + k4];
#pragma unroll
        for (int kk = 0; kk < 4; kk++) {
            float4 w = Wv[((k4 << 2) + kk) * 32 + c];
#pragma unroll
            for (int i = 0; i < 8; i++) {
                float av = kk == 0 ? a[i].x : kk == 1 ? a[i].y : kk == 2 ? a[i].z : a[i].w;
                acc[i].x += av * w.x;
                acc[i].y += av * w.y;
                acc[i].z += av * w.z;
                acc[i].w += av * w.w;
            }
        }
    }

    __half2* Fh2 = (__half2*)feat_h;
#pragma unroll
    for (int i = 0; i < 8; i++) {
        int row = row0 + rg * 8 + i;
        if (row < N) {
            size_t o = ((size_t)row << 6) + (c << 1);
            Fh2[o] = __floats2half2_rn(acc[i].x, acc[i].y);
            Fh2[o + 1] = __floats2half2_rn(acc[i].z, acc[i].w);
        }
    }

    float4 alv = ((const float4*)al)[c];
    float4 arv = ((const float4*)ar)[c];
    float pel[8], per_[8];
#pragma unroll
    for (int i = 0; i < 8; i++) {
        pel[i] = acc[i].x * alv.x + acc[i].y * alv.y + acc[i].z * alv.z + acc[i].w * alv.w;
        per_[i] = acc[i].x * arv.x + acc[i].y * arv.y + acc[i].z * arv.z + acc[i].w * arv.w;
    }
#pragma unroll
    for (int m = 1; m < 8; m <<= 1) {
#pragma unroll
        for (int i = 0; i < 8; i++) {
            pel[i] += __shfl_xor(pel[i], m);
            per_[i] += __shfl_xor(per_[i], m);
        }
    }
    if ((c & 7) == 0) {
        int h = c >> 3;
#pragma unroll
        for (int i = 0; i < 8; i++) {
            int row = row0 + rg * 8 + i;
            if (row < N) {
                el[(row << 2) + h] = pel[i];
                er[(row << 2) + h] = per_[i];
            }
        }
    }
}

// ------- Residual GEMM: C = relu(C + A@W + bias), fp32 (layer 2) -------
template <int K>
__global__ __launch_bounds__(256) void gemm_res_k(const float* __restrict__ A,
                                                  const float* __restrict__ W,
                                                  const float* __restrict__ bias,
                                                  float* __restrict__ C, int N) {
    __shared__ float As[64 * K];
    const int c = threadIdx.x & 31;
    const int rg = threadIdx.x >> 5;
    const int row0 = blockIdx.x << 6;
    const int K4 = K >> 2;

    const float4* Av = (const float4*)A;
    float4* AsV = (float4*)As;
    for (int idx = threadIdx.x; idx < 16 * K; idx += 256) {
        int rr = idx / K4, kk4 = idx - rr * K4;
        int row = row0 + rr;
        float4 v = make_float4(0.f, 0.f, 0.f, 0.f);
        if (row < N) v = Av[(size_t)row * K4 + kk4];
        AsV[rr * K4 + kk4] = v;
    }
    __syncthreads();

    const float4* Wv = (const float4*)W;
    float4 acc[8];
#pragma unroll
    for (int i = 0; i < 8; i++) acc[i] = make_float4(0.f, 0.f, 0.f, 0.f);

    for (int k4 = 0; k4 < K4; k4++) {
        float4 a[8];
#pragma unroll
        for (int i = 0; i < 8; i++) a[i] = AsV[(rg * 8 + i) * K4 + k4];
#pragma unroll
        for (int kk = 0; kk < 4; kk++) {
            float4 w = Wv[((k4 << 2) + kk) * 32 + c];
#pragma unroll
            for (int i = 0; i < 8; i++) {
                float av = kk == 0 ? a[i].x : kk == 1 ? a[i].y : kk == 2 ? a[i].z : a[i].w;
                acc[i].x += av * w.x;
                acc[i].y += av * w.y;
                acc[i].z += av * w.z;
                acc[i].w += av * w.w;
            }
        }
    }

    float4* Cv = (float4*)C;
    float4 bv = ((const float4*)bias)[c];
#pragma unroll
    for (int i = 0; i < 8; i++) {
        int row = row0 + rg * 8 + i;
        if (row < N) {
            size_t o = ((size_t)row << 5) + c;
            float4 cur = Cv[o];
            float4 v;
            v.x = fmaxf(cur.x + acc[i].x + bv.x, 0.f);
            v.y = fmaxf(cur.y + acc[i].y + bv.y, 0.f);
            v.z = fmaxf(cur.z + acc[i].z + bv.z, 0.f);
            v.w = fmaxf(cur.w + acc[i].w + bv.w, 0.f);
            Cv[o] = v;
        }
    }
}

// ---------------- Bucketed CSR build ----------------
// Pass 1: partition edges into per-bucket slabs. Pack (dst<<16)|src in u32
// (both < 65536). Per-block LDS histogram -> one global atomic per
// (block,bucket) -> contiguous run writes into part[b*CAP ...].
__global__ __launch_bounds__(256) void partition_k(const int* __restrict__ src,
                                                   const int* __restrict__ dst,
                                                   int* __restrict__ cursor,
                                                   unsigned* __restrict__ part,
                                                   int E, int NB) {
    __shared__ unsigned stash[PCHUNK];
    __shared__ int hist[512];
    __shared__ int base[512];
    const int tid = threadIdx.x;
    const int e0 = blockIdx.x * PCHUNK;

    for (int i = tid; i < NB; i += 256) hist[i] = 0;
    __syncthreads();

    for (int i = tid; i < PCHUNK; i += 256) {
        int e = e0 + i;
        unsigned pk = 0xFFFFFFFFu;
        if (e < E) {
            int d = dst[e];
            pk = ((unsigned)d << 16) | (unsigned)src[e];
            atomicAdd(&hist[d >> BUCKET_SHIFT], 1);
        }
        stash[i] = pk;
    }
    __syncthreads();

    for (int i = tid; i < NB; i += 256) {
        int hcnt = hist[i];
        base[i] = hcnt ? atomicAdd(&cursor[i], hcnt) : 0;
        hist[i] = 0;  // reuse as intra-block cursor
    }
    __syncthreads();

    for (int i = tid; i < PCHUNK; i += 256) {
        unsigned pk = stash[i];
        if (pk != 0xFFFFFFFFu) {
            int b = pk >> (16 + BUCKET_SHIFT);
            int r = base[b] + atomicAdd(&hist[b], 1);
            if (r < CAP) part[(size_t)b * CAP + r] = pk;
        }
    }
}

// Pass 2: one block per bucket. Coalesced read of the bucket's slab; node
// count/scan/scatter entirely in LDS; coalesced stream-out of the CSR slice
// plus row_beg/row_end (bucket-strided layout -> no global scan needed).
__global__ __launch_bounds__(256) void bucket_csr_k(const int* __restrict__ cursor,
                                                    const unsigned* __restrict__ part,
                                                    int* __restrict__ csr_src,
                                                    int* __restrict__ row_beg,
                                                    int* __restrict__ row_end,
                                                    int N) {
    __shared__ int cnt[128], sc[128], ex[128], cur[128];
    __shared__ int lcsr[CAP];
    const int b = blockIdx.x;
    const int tid = threadIdx.x;
    int m = cursor[b];
    m = m < CAP ? m : CAP;
    if (tid < 128) cnt[tid] = 0;
    __syncthreads();

    const unsigned* pp = part + (size_t)b * CAP;
    for (int i = tid; i < m; i += 256) atomicAdd(&cnt[(pp[i] >> 16) & 127], 1);
    __syncthreads();

    if (tid < 128) sc[tid] = cnt[tid];
    __syncthreads();
    for (int off = 1; off < 128; off <<= 1) {
        int t = (tid < 128 && tid >= off) ? sc[tid - off] : 0;
        __syncthreads();
        if (tid < 128) sc[tid] += t;
        __syncthreads();
    }
    if (tid < 128) {
        ex[tid] = sc[tid] - cnt[tid];
        cur[tid] = 0;
    }
    __syncthreads();

    for (int i = tid; i < m; i += 256) {
        unsigned pk = pp[i];
        int dlo = (pk >> 16) & 127;
        int r = atomicAdd(&cur[dlo], 1);
        lcsr[ex[dlo] + r] = (int)(pk & 0xFFFFu);
    }
    __syncthreads();

    const int gbase = b * CAP;
    for (int i = tid; i < m; i += 256) csr_src[gbase + i] = lcsr[i];
    int n = (b << BUCKET_SHIFT) + tid;
    if (tid < 128 && n < N) {
        row_beg[n] = gbase + ex[tid];
        row_end[n] = gbase + sc[tid];
    }
}

// ---------------- Pull aggregation (H=4, D=32, fp16 feat) ----------------
// One wave per dst node; lane l -> cols 2l,2l+1 (half2 load), head l>>4.
// CSR walk scalarized (readfirstlane -> s_load). Fuses softmax denominator;
// BR fuses bias+relu. Output fp32.
template <bool BR>
__global__ __launch_bounds__(256) void pull2_k(const int* __restrict__ row_beg,
                                               const int* __restrict__ row_end,
                                               const int* __restrict__ csr_src,
                                               const float* __restrict__ el,
                                               const float* __restrict__ er,
                                               const __half* __restrict__ feat_h,
                                               const float* __restrict__ bias,
                                               float* __restrict__ outp, int N) {
    int n = (blockIdx.x << 2) + (threadIdx.x >> 6);
    if (n >= N) return;
    unsigned l = threadIdx.x & 63;
    unsigned h = l >> 4;
    float erd = er[((unsigned)n << 2) + h];
    const __half2* feat2 = (const __half2*)feat_h;
    int beg = __builtin_amdgcn_readfirstlane(row_beg[n]);
    int end = __builtin_amdgcn_readfirstlane(row_end[n]);
    float ax = 0.f, ay = 0.f, den = 0.f;
    int p = beg;
    for (; p + 4 <= end; p += 4) {
        int s0 = csr_src[p], s1 = csr_src[p + 1];
        int s2 = csr_src[p + 2], s3 = csr_src[p + 3];
        float e0 = el[((unsigned)s0 << 2) + h];
        float e1 = el[((unsigned)s1 << 2) + h];
        float e2 = el[((unsigned)s2 << 2) + h];
        float e3 = el[((unsigned)s3 << 2) + h];
        __half2 g0 = feat2[((unsigned)s0 << 6) + l];
        __half2 g1 = feat2[((unsigned)s1 << 6) + l];
        __half2 g2 = feat2[((unsigned)s2 << 6) + l];
        __half2 g3 = feat2[((unsigned)s3 << 6) + l];
        float x0 = e0 + erd, x1 = e1 + erd, x2 = e2 + erd, x3 = e3 + erd;
        x0 = fmaxf(x0, NEG * x0);
        x1 = fmaxf(x1, NEG * x1);
        x2 = fmaxf(x2, NEG * x2);
        x3 = fmaxf(x3, NEG * x3);
        float w0 = __expf(x0), w1 = __expf(x1), w2 = __expf(x2), w3 = __expf(x3);
        float2 f0 = __half22float2(g0), f1 = __half22float2(g1);
        float2 f2 = __half22float2(g2), f3 = __half22float2(g3);
        den += (w0 + w1) + (w2 + w3);
        ax = fmaf(w0, f0.x, ax);
        ay = fmaf(w0, f0.y, ay);
        ax = fmaf(w1, f1.x, ax);
        ay = fmaf(w1, f1.y, ay);
        ax = fmaf(w2, f2.x, ax);
        ay = fmaf(w2, f2.y, ay);
        ax = fmaf(w3, f3.x, ax);
        ay = fmaf(w3, f3.y, ay);
    }
    for (; p < end; p++) {
        int s0 = csr_src[p];
        float e0 = el[((unsigned)s0 << 2) + h];
        __half2 g0 = feat2[((unsigned)s0 << 6) + l];
        float x0 = e0 + erd;
        x0 = fmaxf(x0, NEG * x0);
        float w0 = __expf(x0);
        float2 f0 = __half22float2(g0);
        den += w0;
        ax = fmaf(w0, f0.x, ax);
        ay = fmaf(w0, f0.y, ay);
    }
    float inv = 1.f / den;  // den >= 1 edge (self-loops)
    float2 v;
    v.x = ax * inv;
    v.y = ay * inv;
    if (BR) {
        float2 b = ((const float2*)bias)[l];
        v.x = fmaxf(v.x + b.x, 0.f);
        v.y = fmaxf(v.y + b.y, 0.f);
    }
    ((float2*)outp)[((size_t)n << 6) + l] = v;
}

// Layer 3: feat3 = h3 @ W3 and res3 = h3 @ resW3 + b3 (128 -> 6), one pass.
__global__ __launch_bounds__(256) void feat3res_k(const float* __restrict__ h3,
                                                  const float* __restrict__ W3,
                                                  const float* __restrict__ resW3,
                                                  const float* __restrict__ b3,
                                                  float* __restrict__ feat3,
                                                  float* __restrict__ res3, int N) {
    int n = blockIdx.x * blockDim.x + threadIdx.x;
    if (n >= N) return;
    const float4* a = (const float4*)(h3 + ((size_t)n << 7));
    float f[6], r[6];
#pragma unroll
    for (int h = 0; h < 6; h++) {
        f[h] = 0.f;
        r[h] = b3[h];
    }
    for (int k4 = 0; k4 < 32; k4++) {
        float4 v = a[k4];
        int k = k4 << 2;
#pragma unroll
        for (int h = 0; h < 6; h++) {
            f[h] += v.x * W3[(k + 0) * 6 + h] + v.y * W3[(k + 1) * 6 + h] +
                    v.z * W3[(k + 2) * 6 + h] + v.w * W3[(k + 3) * 6 + h];
            r[h] += v.x * resW3[(k + 0) * 6 + h] + v.y * resW3[(k + 1) * 6 + h] +
                    v.z * resW3[(k + 2) * 6 + h] + v.w * resW3[(k + 3) * 6 + h];
        }
    }
#pragma unroll
    for (int h = 0; h < 6; h++) {
        feat3[n * 6 + h] = f[h];
        res3[n * 6 + h] = r[h];
    }
}

// Layer 3 pull, one thread per (node, head); adds res3. D=1:
// el[s,h] = feat3[s,h]*al3[h], er[d,h] = feat3[d,h]*ar3[h].
__global__ __launch_bounds__(256) void pull6_k(const int* __restrict__ row_beg,
                                               const int* __restrict__ row_end,
                                               const int* __restrict__ csr_src,
                                               const float* __restrict__ feat3,
                                               const float* __restrict__ al3,
                                               const float* __restrict__ ar3,
                                               const float* __restrict__ res3,
                                               float* __restrict__ rst3, int N) {
    int idx = blockIdx.x * blockDim.x + threadIdx.x;
    if (idx >= N * 6) return;
    int n = idx / 6, h = idx - n * 6;
    float a3 = al3[h], r3 = ar3[h];
    float fdr = feat3[idx] * r3;
    int beg = row_beg[n], end = row_end[n];
    float acc = 0.f, den = 0.f;
    int p = beg;
    for (; p + 2 <= end; p += 2) {
        int s0 = csr_src[p], s1 = csr_src[p + 1];
        float f0 = feat3[(unsigned)s0 * 6 + h];
        float f1 = feat3[(unsigned)s1 * 6 + h];
        float x0 = fmaf(f0, a3, fdr);
        float x1 = fmaf(f1, a3, fdr);
        x0 = fmaxf(x0, NEG * x0);
        x1 = fmaxf(x1, NEG * x1);
        float w0 = __expf(x0), w1 = __expf(x1);
        den += w0 + w1;
        acc = fmaf(w0, f0, acc);
        acc = fmaf(w1, f1, acc);
    }
    if (p < end) {
        int s0 = csr_src[p];
        float f0 = feat3[(unsigned)s0 * 6 + h];
        float x0 = fmaf(f0, a3, fdr);
        x0 = fmaxf(x0, NEG * x0);
        float w0 = __expf(x0);
        den += w0;
        acc = fmaf(w0, f0, acc);
    }
    rst3[idx] = acc / den + res3[idx];
}

// Final: mean over 6 heads -> out[n].
__global__ __launch_bounds__(256) void final_k(const float* __restrict__ rst3,
                                               float* __restrict__ out, int N) {
    int n = blockIdx.x * blockDim.x + threadIdx.x;
    if (n >= N) return;
    const float2* r2 = (const float2*)(rst3 + n * 6);
    float2 a = r2[0], b = r2[1], c = r2[2];
    out[n] = (a.x + a.y + b.x + b.y + c.x + c.y) * (1.f / 6.f);
}

extern "C" void kernel_launch(void* const* d_in, const int* in_sizes, int n_in,
                              void* d_out, int out_size, void* d_ws, size_t ws_size,
                              hipStream_t stream) {
    const float* x = (const float*)d_in[0];
    const int* src = (const int*)d_in[1];
    const int* dst = (const int*)d_in[2];
    const float* W1 = (const float*)d_in[3];
    const float* al1 = (const float*)d_in[4];
    const float* ar1 = (const float*)d_in[5];
    const float* b1 = (const float*)d_in[6];
    const float* W2 = (const float*)d_in[7];
    const float* al2 = (const float*)d_in[8];
    const float* ar2 = (const float*)d_in[9];
    const float* b2 = (const float*)d_in[10];
    const float* resW2 = (const float*)d_in[11];
    const float* W3 = (const float*)d_in[12];
    const float* al3 = (const float*)d_in[13];
    const float* ar3 = (const float*)d_in[14];
    const float* b3 = (const float*)d_in[15];
    const float* resW3 = (const float*)d_in[16];
    float* out = (float*)d_out;

    const int N = in_sizes[0] / 64;
    const int E = in_sizes[1];
    const int NB = (N + 127) >> BUCKET_SHIFT;  // 391 for N=50000

    // ---- workspace layout ----
    float* ws = (float*)d_ws;
    __half* feat_h = (__half*)ws;            // N*128 halves == N*64 floats
    float* h2 = ws + (size_t)N * 64;         // N*128 f32
    float* h3 = h2 + (size_t)N * 128;        // N*128 f32
    float* el = h3 + (size_t)N * 128;        // N*4
    float* er = el + (size_t)N * 4;          // N*4
    float* feat3 = el;                       // N*6 aliases el/er (free in layer 3)
    float* res3 = er + (size_t)N * 4;        // N*6
    float* rst3 = res3 + (size_t)N * 6;      // N*6
    int* ip = (int*)(rst3 + (size_t)N * 6);
    int* cursor = ip;                        // 512 (memset)
    int* row_beg = cursor + 512;             // N
    int* row_end = row_beg + N;              // N
    unsigned* part = (unsigned*)(row_end + N);       // NB*CAP
    int* csr_src = (int*)(part + (size_t)NB * CAP);  // NB*CAP

    const int gN = (N + 255) / 256;
    const int gN64 = (N + 63) / 64;
    const int gN6 = (N * 6 + 255) / 256;
    const int gNw = (N + 3) / 4;               // wave-per-node blocks
    const int gP = (E + PCHUNK - 1) / PCHUNK;  // partition blocks

    // ---- build bucketed dst-CSR (shared by all 3 layers) ----
    hipMemsetAsync(cursor, 0, sizeof(int) * 512, stream);
    partition_k<<<gP, 256, 0, stream>>>(src, dst, cursor, part, E, NB);
    bucket_csr_k<<<NB, 256, 0, stream>>>(cursor, part, csr_src, row_beg, row_end, N);

    // ---- Layer 1: 64 -> (4,32), relu, no residual ----
    gemm_el_k<64><<<gN64, 256, 0, stream>>>(x, W1, al1, ar1, feat_h, el, er, N);
    pull2_k<true><<<gNw, 256, 0, stream>>>(row_beg, row_end, csr_src, el, er,
                                           feat_h, b1, h2, N);

    // ---- Layer 2: 128 -> (4,32), relu, residual ----
    gemm_el_k<128><<<gN64, 256, 0, stream>>>(h2, W2, al2, ar2, feat_h, el, er, N);
    pull2_k<false><<<gNw, 256, 0, stream>>>(row_beg, row_end, csr_src, el, er,
                                            feat_h, nullptr, h3, N);
    // h3 = relu(h3 + h2@resW2 + b2)
    gemm_res_k<128><<<gN64, 256, 0, stream>>>(h2, resW2, b2, h3, N);

    // ---- Layer 3: 128 -> (6,1), no act, residual, mean over heads ----
    feat3res_k<<<gN, 256, 0, stream>>>(h3, W3, resW3, b3, feat3, res3, N);
    pull6_k<<<gN6, 256, 0, stream>>>(row_beg, row_end, csr_src, feat3, al3, ar3,
                                     res3, rst3, N);
    final_k<<<gN, 256, 0, stream>>>(rst3, out, N);
}

// Round 7
// 259.938 us; speedup vs baseline: 46.5897x; 1.1649x over previous
//
#include <hip/hip_runtime.h>
#include <hip/hip_fp16.h>

#define NEG 0.2f
#define BUCKET_SHIFT 7
#define CAP 3200
#define PCHUNK 4096

typedef _Float16 h8 __attribute__((ext_vector_type(8)));
typedef float f4v __attribute__((ext_vector_type(4)));

// ------- Layer-1 GEMM (K=64, fp32 VALU) + el/er epilogue, fp16 feat out -------
template <int K>
__global__ __launch_bounds__(256) void gemm_el_k(const float* __restrict__ A,
                                                 const float* __restrict__ W,
                                                 const float* __restrict__ al,
                                                 const float* __restrict__ ar,
                                                 __half* __restrict__ feat_h,
                                                 float* __restrict__ el,
                                                 float* __restrict__ er, int N) {
    __shared__ float As[64 * K];
    const int c = threadIdx.x & 31;
    const int rg = threadIdx.x >> 5;
    const int row0 = blockIdx.x << 6;
    const int K4 = K >> 2;

    const float4* Av = (const float4*)A;
    float4* AsV = (float4*)As;
    for (int idx = threadIdx.x; idx < 16 * K; idx += 256) {
        int rr = idx / K4, kk4 = idx - rr * K4;
        int row = row0 + rr;
        float4 v = make_float4(0.f, 0.f, 0.f, 0.f);
        if (row < N) v = Av[(size_t)row * K4 + kk4];
        AsV[rr * K4 + kk4] = v;
    }
    __syncthreads();

    const float4* Wv = (const float4*)W;
    float4 acc[8];
#pragma unroll
    for (int i = 0; i < 8; i++) acc[i] = make_float4(0.f, 0.f, 0.f, 0.f);

    for (int k4 = 0; k4 < K4; k4++) {
        float4 a[8];
#pragma unroll
        for (int i = 0; i < 8; i++) a[i] = AsV[(rg * 8 + i) * K4 + k4];
#pragma unroll
        for (int kk = 0; kk < 4; kk++) {
            float4 w = Wv[((k4 << 2) + kk) * 32 + c];
#pragma unroll
            for (int i = 0; i < 8; i++) {
                float av = kk == 0 ? a[i].x : kk == 1 ? a[i].y : kk == 2 ? a[i].z : a[i].w;
                acc[i].x += av * w.x;
                acc[i].y += av * w.y;
                acc[i].z += av * w.z;
                acc[i].w += av * w.w;
            }
        }
    }

    __half2* Fh2 = (__half2*)feat_h;
#pragma unroll
    for (int i = 0; i < 8; i++) {
        int row = row0 + rg * 8 + i;
        if (row < N) {
            size_t o = ((size_t)row << 6) + (c << 1);
            Fh2[o] = __floats2half2_rn(acc[i].x, acc[i].y);
            Fh2[o + 1] = __floats2half2_rn(acc[i].z, acc[i].w);
        }
    }

    float4 alv = ((const float4*)al)[c];
    float4 arv = ((const float4*)ar)[c];
    float pel[8], per_[8];
#pragma unroll
    for (int i = 0; i < 8; i++) {
        pel[i] = acc[i].x * alv.x + acc[i].y * alv.y + acc[i].z * alv.z + acc[i].w * alv.w;
        per_[i] = acc[i].x * arv.x + acc[i].y * arv.y + acc[i].z * arv.z + acc[i].w * arv.w;
    }
#pragma unroll
    for (int m = 1; m < 8; m <<= 1) {
#pragma unroll
        for (int i = 0; i < 8; i++) {
            pel[i] += __shfl_xor(pel[i], m);
            per_[i] += __shfl_xor(per_[i], m);
        }
    }
    if ((c & 7) == 0) {
        int h = c >> 3;
#pragma unroll
        for (int i = 0; i < 8; i++) {
            int row = row0 + rg * 8 + i;
            if (row < N) {
                el[(row << 2) + h] = pel[i];
                er[(row << 2) + h] = per_[i];
            }
        }
    }
}

// ------- Weight convert: fp32 W[k][n] (128x128) -> fp16 fragment-order -------
// Chunk c = ((kb*8 + t)*64 + lane); element i: k = kb*32 + (lane>>4)*8 + i,
// n = 16t + (lane&15). Consumed by lane-contiguous ds_read_b128.
__global__ __launch_bounds__(256) void wconv_k(const float* __restrict__ W2,
                                               const float* __restrict__ rW2,
                                               float4* __restrict__ W2f,
                                               float4* __restrict__ rW2f) {
    int c = blockIdx.x * 256 + threadIdx.x;  // 0..4095
    int which = c >> 11;
    int cc = c & 2047;
    int kb = cc >> 9, rem = cc & 511, t = rem >> 6, lane = rem & 63;
    int n = (t << 4) + (lane & 15);
    int k0 = (kb << 5) + ((lane >> 4) << 3);
    const float* S = which ? rW2 : W2;
    h8 v;
#pragma unroll
    for (int i = 0; i < 8; i++) v[i] = (_Float16)S[(k0 + i) * 128 + n];
    ((h8*)(which ? rW2f : W2f))[cc] = v;
}

// ------- MFMA GEMM core helpers (K=128, 64 rows/block, 4 waves) -------
// AsF frag layout: chunk ((w*4+kb)*64 + lane) = A[row0+16w+(lane&15)]
//                  [kb*32 + (lane>>4)*8 .. +8]
#define MFMA_STAGE_AND_LOOP()                                                   \
    const int tid = threadIdx.x;                                                \
    const int row0 = blockIdx.x << 6;                                           \
    for (int i = tid; i < 2048; i += 256) WsF[i] = Wf[i];                       \
    const float4* Afv = (const float4*)A;                                       \
    for (int idx = tid; idx < 1024; idx += 256) {                               \
        int r = idx >> 4, kc = idx & 15;                                        \
        float4 v = make_float4(0.f, 0.f, 0.f, 0.f);                             \
        int row = row0 + r;                                                     \
        if (row < N) v = Afv[(size_t)row * 16 + kc];                            \
        int d = ((r >> 4) * 4 + (kc >> 2)) * 64 + (kc & 3) * 16 + (r & 15);     \
        AsF[d] = v;                                                             \
    }                                                                           \
    __syncthreads();                                                            \
    const int w = tid >> 6;                                                     \
    const int lane = tid & 63;                                                  \
    const h8* Ah = (const h8*)AsF;                                              \
    const h8* Wh = (const h8*)WsF;                                              \
    f4v acc[8];                                                                 \
    _Pragma("unroll") for (int t = 0; t < 8; t++) acc[t] = (f4v){0.f, 0.f, 0.f, 0.f}; \
    _Pragma("unroll") for (int kb = 0; kb < 4; kb++) {                          \
        h8 af = Ah[(w * 4 + kb) * 64 + lane];                                   \
        _Pragma("unroll") for (int t = 0; t < 8; t++) {                         \
            h8 bf = Wh[(kb * 8 + t) * 64 + lane];                               \
            acc[t] = __builtin_amdgcn_mfma_f32_16x16x32_f16(af, bf, acc[t], 0, 0, 0); \
        }                                                                       \
    }                                                                           \
    const int c16 = lane & 15;                                                  \
    const int rg = lane >> 4;

// ------- Layer-2 MFMA GEMM: feat = h2@W2 (fp16 out) + el/er -------
__global__ __launch_bounds__(256) void mfma_el_k(const _Float16* __restrict__ A,
                                                 const float4* __restrict__ Wf,
                                                 const float* __restrict__ al,
                                                 const float* __restrict__ ar,
                                                 _Float16* __restrict__ feat,
                                                 float* __restrict__ el,
                                                 float* __restrict__ er, int N) {
    __shared__ float4 WsF[2048];
    __shared__ float4 AsF[1024];
    MFMA_STAGE_AND_LOOP()

    // el/er: head = col>>5, col = 16t + c16 -> head = t>>1
    float alv[8], arv[8];
#pragma unroll
    for (int t = 0; t < 8; t++) {
        alv[t] = al[(t << 4) + c16];
        arv[t] = ar[(t << 4) + c16];
    }
    float pel[4][4], per_[4][4];  // [j][head]
#pragma unroll
    for (int j = 0; j < 4; j++)
#pragma unroll
        for (int hh = 0; hh < 4; hh++) {
            pel[j][hh] = acc[2 * hh][j] * alv[2 * hh] + acc[2 * hh + 1][j] * alv[2 * hh + 1];
            per_[j][hh] = acc[2 * hh][j] * arv[2 * hh] + acc[2 * hh + 1][j] * arv[2 * hh + 1];
        }
#pragma unroll
    for (int m = 1; m < 16; m <<= 1)
#pragma unroll
        for (int j = 0; j < 4; j++)
#pragma unroll
            for (int hh = 0; hh < 4; hh++) {
                pel[j][hh] += __shfl_xor(pel[j][hh], m);
                per_[j][hh] += __shfl_xor(per_[j][hh], m);
            }
    if (c16 == 0) {
#pragma unroll
        for (int j = 0; j < 4; j++) {
            int row = row0 + (w << 4) + (rg << 2) + j;
            if (row < N) {
                ((float4*)el)[row] = make_float4(pel[j][0], pel[j][1], pel[j][2], pel[j][3]);
                ((float4*)er)[row] = make_float4(per_[j][0], per_[j][1], per_[j][2], per_[j][3]);
            }
        }
    }

    // feat fp16 via wave-local LDS bounce (reuse this wave's AsF region)
    _Float16* As2 = (_Float16*)AsF + (w << 11);  // 4 KB region
#pragma unroll
    for (int t = 0; t < 8; t++)
#pragma unroll
        for (int j = 0; j < 4; j++)
            As2[((rg << 2) + j) * 128 + (t << 4) + c16] = (_Float16)acc[t][j];
    __asm__ volatile("s_waitcnt lgkmcnt(0)" ::: "memory");
    const float4* As2v = (const float4*)As2;
    float4* featv = (float4*)feat;  // 8 halfs per chunk
#pragma unroll
    for (int ii = 0; ii < 4; ii++) {
        int ch = ii * 64 + lane;
        int row = row0 + (w << 4) + (ch >> 4);
        if (row < N) featv[(size_t)row * 16 + (ch & 15)] = As2v[ch];
    }
}

// ------- Layer-2 residual + Layer-3 projections, fused -------
// h3 = relu(rsth + h2@resW2 + b2) kept in registers;
// feat3 = h3@W3, res3 = h3@resW3 + b3 (128 -> 6 each). h3 never stored.
__global__ __launch_bounds__(256) void mfma_res_k(const _Float16* __restrict__ A,
                                                  const float4* __restrict__ Wf,
                                                  const _Float16* __restrict__ rsth,
                                                  const float* __restrict__ b2,
                                                  const float* __restrict__ W3,
                                                  const float* __restrict__ resW3,
                                                  const float* __restrict__ b3,
                                                  float* __restrict__ feat3,
                                                  float* __restrict__ res3, int N) {
    __shared__ float4 WsF[2048];
    __shared__ float4 AsF[1024];
    MFMA_STAGE_AND_LOOP()

    // stage rsth tile wave-local into this wave's AsF region (coalesced)
    float4* As2v = (float4*)AsF + (w << 8);
#pragma unroll
    for (int ii = 0; ii < 4; ii++) {
        int ch = ii * 64 + lane;
        int row = row0 + (w << 4) + (ch >> 4);
        float4 v = make_float4(0.f, 0.f, 0.f, 0.f);
        if (row < N) v = ((const float4*)rsth)[(size_t)row * 16 + (ch & 15)];
        As2v[ch] = v;
    }
    __asm__ volatile("s_waitcnt lgkmcnt(0)" ::: "memory");
    const _Float16* As2 = (const _Float16*)As2v;

    float b2v[8];
#pragma unroll
    for (int t = 0; t < 8; t++) b2v[t] = b2[(t << 4) + c16];

    float hv[8][4];
#pragma unroll
    for (int t = 0; t < 8; t++)
#pragma unroll
        for (int j = 0; j < 4; j++) {
            float rv = (float)As2[((rg << 2) + j) * 128 + (t << 4) + c16];
            hv[t][j] = fmaxf(acc[t][j] + rv + b2v[t], 0.f);
        }

    float f3[4][6], r3[4][6];
#pragma unroll
    for (int j = 0; j < 4; j++)
#pragma unroll
        for (int h = 0; h < 6; h++) {
            f3[j][h] = 0.f;
            r3[j][h] = 0.f;
        }
#pragma unroll
    for (int t = 0; t < 8; t++) {
        int col = (t << 4) + c16;
        const float* w3p = W3 + col * 6;
        const float* rwp = resW3 + col * 6;
#pragma unroll
        for (int h = 0; h < 6; h++) {
            float w3 = w3p[h], rw = rwp[h];
#pragma unroll
            for (int j = 0; j < 4; j++) {
                f3[j][h] = fmaf(hv[t][j], w3, f3[j][h]);
                r3[j][h] = fmaf(hv[t][j], rw, r3[j][h]);
            }
        }
    }
#pragma unroll
    for (int m = 1; m < 16; m <<= 1)
#pragma unroll
        for (int j = 0; j < 4; j++)
#pragma unroll
            for (int h = 0; h < 6; h++) {
                f3[j][h] += __shfl_xor(f3[j][h], m);
                r3[j][h] += __shfl_xor(r3[j][h], m);
            }
    if (c16 == 0) {
#pragma unroll
        for (int j = 0; j < 4; j++) {
            int row = row0 + (w << 4) + (rg << 2) + j;
            if (row < N) {
#pragma unroll
                for (int h = 0; h < 6; h++) {
                    feat3[row * 6 + h] = f3[j][h];
                    res3[row * 6 + h] = r3[j][h] + b3[h];
                }
            }
        }
    }
}

// ---------------- Bucketed CSR build ----------------
__global__ __launch_bounds__(256) void partition_k(const int* __restrict__ src,
                                                   const int* __restrict__ dst,
                                                   int* __restrict__ cursor,
                                                   unsigned* __restrict__ part,
                                                   int E, int NB) {
    __shared__ unsigned stash[PCHUNK];
    __shared__ int hist[512];
    __shared__ int base[512];
    const int tid = threadIdx.x;
    const int e0 = blockIdx.x * PCHUNK;

    for (int i = tid; i < NB; i += 256) hist[i] = 0;
    __syncthreads();

    for (int i = tid; i < PCHUNK; i += 256) {
        int e = e0 + i;
        unsigned pk = 0xFFFFFFFFu;
        if (e < E) {
            int d = dst[e];
            pk = ((unsigned)d << 16) | (unsigned)src[e];
            atomicAdd(&hist[d >> BUCKET_SHIFT], 1);
        }
        stash[i] = pk;
    }
    __syncthreads();

    for (int i = tid; i < NB; i += 256) {
        int hcnt = hist[i];
        base[i] = hcnt ? atomicAdd(&cursor[i], hcnt) : 0;
        hist[i] = 0;
    }
    __syncthreads();

    for (int i = tid; i < PCHUNK; i += 256) {
        unsigned pk = stash[i];
        if (pk != 0xFFFFFFFFu) {
            int b = pk >> (16 + BUCKET_SHIFT);
            int r = base[b] + atomicAdd(&hist[b], 1);
            if (r < CAP) part[(size_t)b * CAP + r] = pk;
        }
    }
}

__global__ __launch_bounds__(256) void bucket_csr_k(const int* __restrict__ cursor,
                                                    const unsigned* __restrict__ part,
                                                    int* __restrict__ csr_src,
                                                    int* __restrict__ row_beg,
                                                    int* __restrict__ row_end,
                                                    int N) {
    __shared__ int cnt[128], sc[128], ex[128], cur[128];
    __shared__ int lcsr[CAP];
    const int b = blockIdx.x;
    const int tid = threadIdx.x;
    int m = cursor[b];
    m = m < CAP ? m : CAP;
    if (tid < 128) cnt[tid] = 0;
    __syncthreads();

    const unsigned* pp = part + (size_t)b * CAP;
    for (int i = tid; i < m; i += 256) atomicAdd(&cnt[(pp[i] >> 16) & 127], 1);
    __syncthreads();

    if (tid < 128) sc[tid] = cnt[tid];
    __syncthreads();
    for (int off = 1; off < 128; off <<= 1) {
        int t = (tid < 128 && tid >= off) ? sc[tid - off] : 0;
        __syncthreads();
        if (tid < 128) sc[tid] += t;
        __syncthreads();
    }
    if (tid < 128) {
        ex[tid] = sc[tid] - cnt[tid];
        cur[tid] = 0;
    }
    __syncthreads();

    for (int i = tid; i < m; i += 256) {
        unsigned pk = pp[i];
        int dlo = (pk >> 16) & 127;
        int r = atomicAdd(&cur[dlo], 1);
        lcsr[ex[dlo] + r] = (int)(pk & 0xFFFFu);
    }
    __syncthreads();

    const int gbase = b * CAP;
    for (int i = tid; i < m; i += 256) csr_src[gbase + i] = lcsr[i];
    int n = (b << BUCKET_SHIFT) + tid;
    if (tid < 128 && n < N) {
        row_beg[n] = gbase + ex[tid];
        row_end[n] = gbase + sc[tid];
    }
}

// ---------------- Pull aggregation (H=4, D=32, fp16 in, fp16 out) ----------------
template <bool BR>
__global__ __launch_bounds__(256) void pull2_k(const int* __restrict__ row_beg,
                                               const int* __restrict__ row_end,
                                               const int* __restrict__ csr_src,
                                               const float* __restrict__ el,
                                               const float* __restrict__ er,
                                               const __half* __restrict__ feat_h,
                                               const float* __restrict__ bias,
                                               __half* __restrict__ outp, int N) {
    int n = (blockIdx.x << 2) + (threadIdx.x >> 6);
    if (n >= N) return;
    unsigned l = threadIdx.x & 63;
    unsigned h = l >> 4;
    float erd = er[((unsigned)n << 2) + h];
    const __half2* feat2 = (const __half2*)feat_h;
    int beg = __builtin_amdgcn_readfirstlane(row_beg[n]);
    int end = __builtin_amdgcn_readfirstlane(row_end[n]);
    float ax = 0.f, ay = 0.f, den = 0.f;
    int p = beg;
    for (; p + 4 <= end; p += 4) {
        int s0 = csr_src[p], s1 = csr_src[p + 1];
        int s2 = csr_src[p + 2], s3 = csr_src[p + 3];
        float e0 = el[((unsigned)s0 << 2) + h];
        float e1 = el[((unsigned)s1 << 2) + h];
        float e2 = el[((unsigned)s2 << 2) + h];
        float e3 = el[((unsigned)s3 << 2) + h];
        __half2 g0 = feat2[((unsigned)s0 << 6) + l];
        __half2 g1 = feat2[((unsigned)s1 << 6) + l];
        __half2 g2 = feat2[((unsigned)s2 << 6) + l];
        __half2 g3 = feat2[((unsigned)s3 << 6) + l];
        float x0 = e0 + erd, x1 = e1 + erd, x2 = e2 + erd, x3 = e3 + erd;
        x0 = fmaxf(x0, NEG * x0);
        x1 = fmaxf(x1, NEG * x1);
        x2 = fmaxf(x2, NEG * x2);
        x3 = fmaxf(x3, NEG * x3);
        float w0 = __expf(x0), w1 = __expf(x1), w2 = __expf(x2), w3 = __expf(x3);
        float2 f0 = __half22float2(g0), f1 = __half22float2(g1);
        float2 f2 = __half22float2(g2), f3 = __half22float2(g3);
        den += (w0 + w1) + (w2 + w3);
        ax = fmaf(w0, f0.x, ax);
        ay = fmaf(w0, f0.y, ay);
        ax = fmaf(w1, f1.x, ax);
        ay = fmaf(w1, f1.y, ay);
        ax = fmaf(w2, f2.x, ax);
        ay = fmaf(w2, f2.y, ay);
        ax = fmaf(w3, f3.x, ax);
        ay = fmaf(w3, f3.y, ay);
    }
    for (; p < end; p++) {
        int s0 = csr_src[p];
        float e0 = el[((unsigned)s0 << 2) + h];
        __half2 g0 = feat2[((unsigned)s0 << 6) + l];
        float x0 = e0 + erd;
        x0 = fmaxf(x0, NEG * x0);
        float w0 = __expf(x0);
        float2 f0 = __half22float2(g0);
        den += w0;
        ax = fmaf(w0, f0.x, ax);
        ay = fmaf(w0, f0.y, ay);
    }
    float inv = 1.f / den;  // den >= 1 edge (self-loops)
    float vx = ax * inv, vy = ay * inv;
    if (BR) {
        float2 b = ((const float2*)bias)[l];
        vx = fmaxf(vx + b.x, 0.f);
        vy = fmaxf(vy + b.y, 0.f);
    }
    ((__half2*)outp)[((size_t)n << 6) + l] = __floats2half2_rn(vx, vy);
}

// Layer 3 pull, one thread per (node, head); adds res3. D=1.
__global__ __launch_bounds__(256) void pull6_k(const int* __restrict__ row_beg,
                                               const int* __restrict__ row_end,
                                               const int* __restrict__ csr_src,
                                               const float* __restrict__ feat3,
                                               const float* __restrict__ al3,
                                               const float* __restrict__ ar3,
                                               const float* __restrict__ res3,
                                               float* __restrict__ rst3, int N) {
    int idx = blockIdx.x * blockDim.x + threadIdx.x;
    if (idx >= N * 6) return;
    int n = idx / 6, h = idx - n * 6;
    float a3 = al3[h], r3 = ar3[h];
    float fdr = feat3[idx] * r3;
    int beg = row_beg[n], end = row_end[n];
    float acc = 0.f, den = 0.f;
    int p = beg;
    for (; p + 2 <= end; p += 2) {
        int s0 = csr_src[p], s1 = csr_src[p + 1];
        float f0 = feat3[(unsigned)s0 * 6 + h];
        float f1 = feat3[(unsigned)s1 * 6 + h];
        float x0 = fmaf(f0, a3, fdr);
        float x1 = fmaf(f1, a3, fdr);
        x0 = fmaxf(x0, NEG * x0);
        x1 = fmaxf(x1, NEG * x1);
        float w0 = __expf(x0), w1 = __expf(x1);
        den += w0 + w1;
        acc = fmaf(w0, f0, acc);
        acc = fmaf(w1, f1, acc);
    }
    if (p < end) {
        int s0 = csr_src[p];
        float f0 = feat3[(unsigned)s0 * 6 + h];
        float x0 = fmaf(f0, a3, fdr);
        x0 = fmaxf(x0, NEG * x0);
        float w0 = __expf(x0);
        den += w0;
        acc = fmaf(w0, f0, acc);
    }
    rst3[idx] = acc / den + res3[idx];
}

// Final: mean over 6 heads -> out[n].
__global__ __launch_bounds__(256) void final_k(const float* __restrict__ rst3,
                                               float* __restrict__ out, int N) {
    int n = blockIdx.x * blockDim.x + threadIdx.x;
    if (n >= N) return;
    const float2* r2 = (const float2*)(rst3 + n * 6);
    float2 a = r2[0], b = r2[1], c = r2[2];
    out[n] = (a.x + a.y + b.x + b.y + c.x + c.y) * (1.f / 6.f);
}

extern "C" void kernel_launch(void* const* d_in, const int* in_sizes, int n_in,
                              void* d_out, int out_size, void* d_ws, size_t ws_size,
                              hipStream_t stream) {
    const float* x = (const float*)d_in[0];
    const int* src = (const int*)d_in[1];
    const int* dst = (const int*)d_in[2];
    const float* W1 = (const float*)d_in[3];
    const float* al1 = (const float*)d_in[4];
    const float* ar1 = (const float*)d_in[5];
    const float* b1 = (const float*)d_in[6];
    const float* W2 = (const float*)d_in[7];
    const float* al2 = (const float*)d_in[8];
    const float* ar2 = (const float*)d_in[9];
    const float* b2 = (const float*)d_in[10];
    const float* resW2 = (const float*)d_in[11];
    const float* W3 = (const float*)d_in[12];
    const float* al3 = (const float*)d_in[13];
    const float* ar3 = (const float*)d_in[14];
    const float* b3 = (const float*)d_in[15];
    const float* resW3 = (const float*)d_in[16];
    float* out = (float*)d_out;

    const int N = in_sizes[0] / 64;
    const int E = in_sizes[1];
    const int NB = (N + 127) >> BUCKET_SHIFT;

    // ---- workspace layout (float units) ----
    float* ws = (float*)d_ws;
    __half* featA = (__half*)ws;                  // N*128 fp16  (layers 1&2 feat)
    __half* h2h = (__half*)(ws + (size_t)N * 64);    // N*128 fp16 (layer-1 out)
    __half* rsth = (__half*)(ws + (size_t)N * 128);  // N*128 fp16 (layer-2 agg out)
    float* el = ws + (size_t)N * 192;             // N*4
    float* er = el + (size_t)N * 4;               // N*4
    float* feat3 = el;                            // N*6 aliases el/er in layer 3
    float* res3 = ws + (size_t)N * 200;           // N*6
    float* rst3 = res3 + (size_t)N * 6;           // N*6
    float* W2f = rst3 + (size_t)N * 6;            // 8192 (2048 float4)
    float* rW2f = W2f + 8192;                     // 8192
    int* ip = (int*)(rW2f + 8192);
    int* cursor = ip;                             // 512 (memset)
    int* row_beg = cursor + 512;                  // N
    int* row_end = row_beg + N;                   // N
    unsigned* part = (unsigned*)(row_end + N);        // NB*CAP
    int* csr_src = (int*)(part + (size_t)NB * CAP);   // NB*CAP

    const int gN = (N + 255) / 256;
    const int gN64 = (N + 63) / 64;
    const int gN6 = (N * 6 + 255) / 256;
    const int gNw = (N + 3) / 4;
    const int gP = (E + PCHUNK - 1) / PCHUNK;

    // ---- weight fragments + bucketed dst-CSR ----
    hipMemsetAsync(cursor, 0, sizeof(int) * 512, stream);
    wconv_k<<<16, 256, 0, stream>>>(W2, resW2, (float4*)W2f, (float4*)rW2f);
    partition_k<<<gP, 256, 0, stream>>>(src, dst, cursor, part, E, NB);
    bucket_csr_k<<<NB, 256, 0, stream>>>(cursor, part, csr_src, row_beg, row_end, N);

    // ---- Layer 1: 64 -> (4,32), relu, no residual ----
    gemm_el_k<64><<<gN64, 256, 0, stream>>>(x, W1, al1, ar1, featA, el, er, N);
    pull2_k<true><<<gNw, 256, 0, stream>>>(row_beg, row_end, csr_src, el, er,
                                           featA, b1, h2h, N);

    // ---- Layer 2: 128 -> (4,32), relu, residual (MFMA) ----
    mfma_el_k<<<gN64, 256, 0, stream>>>((const _Float16*)h2h, (const float4*)W2f,
                                        al2, ar2, (_Float16*)featA, el, er, N);
    pull2_k<false><<<gNw, 256, 0, stream>>>(row_beg, row_end, csr_src, el, er,
                                            featA, nullptr, rsth, N);
    // h3 = relu(rsth + h2@resW2 + b2) fused with layer-3 projections
    mfma_res_k<<<gN64, 256, 0, stream>>>((const _Float16*)h2h, (const float4*)rW2f,
                                         (const _Float16*)rsth, b2, W3, resW3, b3,
                                         feat3, res3, N);

    // ---- Layer 3: pull + residual + mean ----
    pull6_k<<<gN6, 256, 0, stream>>>(row_beg, row_end, csr_src, feat3, al3, ar3,
                                     res3, rst3, N);
    final_k<<<gN, 256, 0, stream>>>(rst3, out, N);
}

// Round 8
// 253.744 us; speedup vs baseline: 47.7270x; 1.0244x over previous
//
#include <hip/hip_runtime.h>
#include <hip/hip_fp16.h>

#define NEG 0.2f
#define BUCKET_SHIFT 7
#define CAP 3200
#define PCHUNK 4096

typedef _Float16 h8 __attribute__((ext_vector_type(8)));
typedef float f4v __attribute__((ext_vector_type(4)));

// ============ device bodies for the fused stage kernels ============

// Weight convert: fp32 W[k][n] (128x128) -> fp16 fragment-order.
// Chunk cc = ((kb*8 + t)*64 + lane); element i: k = kb*32 + (lane>>4)*8 + i,
// n = 16t + (lane&15). Consumed by lane-contiguous ds_read_b128.
__device__ __forceinline__ void wconv_dev(int bid, const float* __restrict__ W2,
                                          const float* __restrict__ rW2,
                                          float4* __restrict__ W2f,
                                          float4* __restrict__ rW2f) {
    int c = bid * 256 + threadIdx.x;  // 0..4095
    int which = c >> 11;
    int cc = c & 2047;
    int kb = cc >> 9, rem = cc & 511, t = rem >> 6, lane = rem & 63;
    int n = (t << 4) + (lane & 15);
    int k0 = (kb << 5) + ((lane >> 4) << 3);
    const float* S = which ? rW2 : W2;
    h8 v;
#pragma unroll
    for (int i = 0; i < 8; i++) v[i] = (_Float16)S[(k0 + i) * 128 + n];
    ((h8*)(which ? rW2f : W2f))[cc] = v;
}

// Partition edges into per-bucket slabs. LDS histogram -> one global atomic
// per (block,bucket) -> contiguous run writes. smem >= 20480 B.
__device__ __forceinline__ void partition_dev(char* smem, int bid,
                                              const int* __restrict__ src,
                                              const int* __restrict__ dst,
                                              int* __restrict__ cursor,
                                              unsigned* __restrict__ part,
                                              int E, int NB) {
    unsigned* stash = (unsigned*)smem;            // PCHUNK
    int* hist = (int*)(smem + PCHUNK * 4);        // 512
    int* base = hist + 512;                       // 512
    const int tid = threadIdx.x;
    const int e0 = bid * PCHUNK;

    for (int i = tid; i < NB; i += 256) hist[i] = 0;
    __syncthreads();

    for (int i = tid; i < PCHUNK; i += 256) {
        int e = e0 + i;
        unsigned pk = 0xFFFFFFFFu;
        if (e < E) {
            int d = dst[e];
            pk = ((unsigned)d << 16) | (unsigned)src[e];
            atomicAdd(&hist[d >> BUCKET_SHIFT], 1);
        }
        stash[i] = pk;
    }
    __syncthreads();

    for (int i = tid; i < NB; i += 256) {
        int hcnt = hist[i];
        base[i] = hcnt ? atomicAdd(&cursor[i], hcnt) : 0;
        hist[i] = 0;  // reuse as intra-block cursor
    }
    __syncthreads();

    for (int i = tid; i < PCHUNK; i += 256) {
        unsigned pk = stash[i];
        if (pk != 0xFFFFFFFFu) {
            int b = pk >> (16 + BUCKET_SHIFT);
            int r = base[b] + atomicAdd(&hist[b], 1);
            if (r < CAP) part[(size_t)b * CAP + r] = pk;
        }
    }
}

// One block per bucket: node count/scan/scatter entirely in LDS; coalesced
// stream-out of the CSR slice + row_beg/row_end. smem >= 14848 B.
__device__ __forceinline__ void bucket_dev(char* smem, int b,
                                           const int* __restrict__ cursor,
                                           const unsigned* __restrict__ part,
                                           int* __restrict__ csr_src,
                                           int* __restrict__ row_beg,
                                           int* __restrict__ row_end, int N) {
    int* cnt = (int*)smem;        // 128
    int* sc = cnt + 128;          // 128
    int* ex = sc + 128;           // 128
    int* cur = ex + 128;          // 128
    int* lcsr = cur + 128;        // CAP
    const int tid = threadIdx.x;
    int m = cursor[b];
    m = m < CAP ? m : CAP;
    if (tid < 128) cnt[tid] = 0;
    __syncthreads();

    const unsigned* pp = part + (size_t)b * CAP;
    for (int i = tid; i < m; i += 256) atomicAdd(&cnt[(pp[i] >> 16) & 127], 1);
    __syncthreads();

    if (tid < 128) sc[tid] = cnt[tid];
    __syncthreads();
    for (int off = 1; off < 128; off <<= 1) {
        int t = (tid < 128 && tid >= off) ? sc[tid - off] : 0;
        __syncthreads();
        if (tid < 128) sc[tid] += t;
        __syncthreads();
    }
    if (tid < 128) {
        ex[tid] = sc[tid] - cnt[tid];
        cur[tid] = 0;
    }
    __syncthreads();

    for (int i = tid; i < m; i += 256) {
        unsigned pk = pp[i];
        int dlo = (pk >> 16) & 127;
        int r = atomicAdd(&cur[dlo], 1);
        lcsr[ex[dlo] + r] = (int)(pk & 0xFFFFu);
    }
    __syncthreads();

    const int gbase = b * CAP;
    for (int i = tid; i < m; i += 256) csr_src[gbase + i] = lcsr[i];
    int n = (b << BUCKET_SHIFT) + tid;
    if (tid < 128 && n < N) {
        row_beg[n] = gbase + ex[tid];
        row_end[n] = gbase + sc[tid];
    }
}

// Layer-1 GEMM (K=64, fp32 VALU) + el/er epilogue, fp16 feat out.
// smem >= 16384 B.
__device__ __forceinline__ void gemm_el_dev(char* smem, int bid,
                                            const float* __restrict__ A,
                                            const float* __restrict__ W,
                                            const float* __restrict__ al,
                                            const float* __restrict__ ar,
                                            __half* __restrict__ feat_h,
                                            float* __restrict__ el,
                                            float* __restrict__ er, int N) {
    constexpr int K = 64;
    float* As = (float*)smem;  // 64*K
    const int c = threadIdx.x & 31;
    const int rg = threadIdx.x >> 5;
    const int row0 = bid << 6;
    const int K4 = K >> 2;

    const float4* Av = (const float4*)A;
    float4* AsV = (float4*)As;
    for (int idx = threadIdx.x; idx < 16 * K; idx += 256) {
        int rr = idx / K4, kk4 = idx - rr * K4;
        int row = row0 + rr;
        float4 v = make_float4(0.f, 0.f, 0.f, 0.f);
        if (row < N) v = Av[(size_t)row * K4 + kk4];
        AsV[rr * K4 + kk4] = v;
    }
    __syncthreads();

    const float4* Wv = (const float4*)W;
    float4 acc[8];
#pragma unroll
    for (int i = 0; i < 8; i++) acc[i] = make_float4(0.f, 0.f, 0.f, 0.f);

    for (int k4 = 0; k4 < K4; k4++) {
        float4 a[8];
#pragma unroll
        for (int i = 0; i < 8; i++) a[i] = AsV[(rg * 8 + i) * K4 + k4];
#pragma unroll
        for (int kk = 0; kk < 4; kk++) {
            float4 w = Wv[((k4 << 2) + kk) * 32 + c];
#pragma unroll
            for (int i = 0; i < 8; i++) {
                float av = kk == 0 ? a[i].x : kk == 1 ? a[i].y : kk == 2 ? a[i].z : a[i].w;
                acc[i].x += av * w.x;
                acc[i].y += av * w.y;
                acc[i].z += av * w.z;
                acc[i].w += av * w.w;
            }
        }
    }

    __half2* Fh2 = (__half2*)feat_h;
#pragma unroll
    for (int i = 0; i < 8; i++) {
        int row = row0 + rg * 8 + i;
        if (row < N) {
            size_t o = ((size_t)row << 6) + (c << 1);
            Fh2[o] = __floats2half2_rn(acc[i].x, acc[i].y);
            Fh2[o + 1] = __floats2half2_rn(acc[i].z, acc[i].w);
        }
    }

    float4 alv = ((const float4*)al)[c];
    float4 arv = ((const float4*)ar)[c];
    float pel[8], per_[8];
#pragma unroll
    for (int i = 0; i < 8; i++) {
        pel[i] = acc[i].x * alv.x + acc[i].y * alv.y + acc[i].z * alv.z + acc[i].w * alv.w;
        per_[i] = acc[i].x * arv.x + acc[i].y * arv.y + acc[i].z * arv.z + acc[i].w * arv.w;
    }
#pragma unroll
    for (int m = 1; m < 8; m <<= 1) {
#pragma unroll
        for (int i = 0; i < 8; i++) {
            pel[i] += __shfl_xor(pel[i], m);
            per_[i] += __shfl_xor(per_[i], m);
        }
    }
    if ((c & 7) == 0) {
        int h = c >> 3;
#pragma unroll
        for (int i = 0; i < 8; i++) {
            int row = row0 + rg * 8 + i;
            if (row < N) {
                el[(row << 2) + h] = pel[i];
                er[(row << 2) + h] = per_[i];
            }
        }
    }
}

// ============ fused stage kernels (independent work, one dispatch) ============
__global__ __launch_bounds__(256) void stage1_k(const float* __restrict__ W2,
                                                const float* __restrict__ rW2,
                                                float4* __restrict__ W2f,
                                                float4* __restrict__ rW2f,
                                                const int* __restrict__ src,
                                                const int* __restrict__ dst,
                                                int* __restrict__ cursor,
                                                unsigned* __restrict__ part,
                                                int E, int NB) {
    __shared__ __align__(16) char smem[20480];
    if (blockIdx.x < 16)
        wconv_dev(blockIdx.x, W2, rW2, W2f, rW2f);
    else
        partition_dev(smem, blockIdx.x - 16, src, dst, cursor, part, E, NB);
}

__global__ __launch_bounds__(256) void stage2_k(const int* __restrict__ cursor,
                                                const unsigned* __restrict__ part,
                                                int* __restrict__ csr_src,
                                                int* __restrict__ row_beg,
                                                int* __restrict__ row_end, int NB,
                                                const float* __restrict__ x,
                                                const float* __restrict__ W1,
                                                const float* __restrict__ al1,
                                                const float* __restrict__ ar1,
                                                __half* __restrict__ featA,
                                                float* __restrict__ el,
                                                float* __restrict__ er, int N) {
    __shared__ __align__(16) char smem[16384];
    if ((int)blockIdx.x < NB)
        bucket_dev(smem, blockIdx.x, cursor, part, csr_src, row_beg, row_end, N);
    else
        gemm_el_dev(smem, blockIdx.x - NB, x, W1, al1, ar1, featA, el, er, N);
}

// ------- MFMA GEMM core (K=128, 64 rows/block, 4 waves) -------
#define MFMA_STAGE_AND_LOOP()                                                   \
    const int tid = threadIdx.x;                                                \
    const int row0 = blockIdx.x << 6;                                           \
    for (int i = tid; i < 2048; i += 256) WsF[i] = Wf[i];                       \
    const float4* Afv = (const float4*)A;                                       \
    for (int idx = tid; idx < 1024; idx += 256) {                               \
        int r = idx >> 4, kc = idx & 15;                                        \
        float4 v = make_float4(0.f, 0.f, 0.f, 0.f);                             \
        int row = row0 + r;                                                     \
        if (row < N) v = Afv[(size_t)row * 16 + kc];                            \
        int d = ((r >> 4) * 4 + (kc >> 2)) * 64 + (kc & 3) * 16 + (r & 15);     \
        AsF[d] = v;                                                             \
    }                                                                           \
    __syncthreads();                                                            \
    const int w = tid >> 6;                                                     \
    const int lane = tid & 63;                                                  \
    const h8* Ah = (const h8*)AsF;                                              \
    const h8* Wh = (const h8*)WsF;                                              \
    f4v acc[8];                                                                 \
    _Pragma("unroll") for (int t = 0; t < 8; t++) acc[t] = (f4v){0.f, 0.f, 0.f, 0.f}; \
    _Pragma("unroll") for (int kb = 0; kb < 4; kb++) {                          \
        h8 af = Ah[(w * 4 + kb) * 64 + lane];                                   \
        _Pragma("unroll") for (int t = 0; t < 8; t++) {                         \
            h8 bf = Wh[(kb * 8 + t) * 64 + lane];                               \
            acc[t] = __builtin_amdgcn_mfma_f32_16x16x32_f16(af, bf, acc[t], 0, 0, 0); \
        }                                                                       \
    }                                                                           \
    const int c16 = lane & 15;                                                  \
    const int rg = lane >> 4;

// Layer-2 MFMA GEMM: feat = h2@W2 (fp16 out) + el/er epilogue.
__global__ __launch_bounds__(256) void mfma_el_k(const _Float16* __restrict__ A,
                                                 const float4* __restrict__ Wf,
                                                 const float* __restrict__ al,
                                                 const float* __restrict__ ar,
                                                 _Float16* __restrict__ feat,
                                                 float* __restrict__ el,
                                                 float* __restrict__ er, int N) {
    __shared__ float4 WsF[2048];
    __shared__ float4 AsF[1024];
    MFMA_STAGE_AND_LOOP()

    float alv[8], arv[8];
#pragma unroll
    for (int t = 0; t < 8; t++) {
        alv[t] = al[(t << 4) + c16];
        arv[t] = ar[(t << 4) + c16];
    }
    float pel[4][4], per_[4][4];
#pragma unroll
    for (int j = 0; j < 4; j++)
#pragma unroll
        for (int hh = 0; hh < 4; hh++) {
            pel[j][hh] = acc[2 * hh][j] * alv[2 * hh] + acc[2 * hh + 1][j] * alv[2 * hh + 1];
            per_[j][hh] = acc[2 * hh][j] * arv[2 * hh] + acc[2 * hh + 1][j] * arv[2 * hh + 1];
        }
#pragma unroll
    for (int m = 1; m < 16; m <<= 1)
#pragma unroll
        for (int j = 0; j < 4; j++)
#pragma unroll
            for (int hh = 0; hh < 4; hh++) {
                pel[j][hh] += __shfl_xor(pel[j][hh], m);
                per_[j][hh] += __shfl_xor(per_[j][hh], m);
            }
    if (c16 == 0) {
#pragma unroll
        for (int j = 0; j < 4; j++) {
            int row = row0 + (w << 4) + (rg << 2) + j;
            if (row < N) {
                ((float4*)el)[row] = make_float4(pel[j][0], pel[j][1], pel[j][2], pel[j][3]);
                ((float4*)er)[row] = make_float4(per_[j][0], per_[j][1], per_[j][2], per_[j][3]);
            }
        }
    }

    _Float16* As2 = (_Float16*)AsF + (w << 11);
#pragma unroll
    for (int t = 0; t < 8; t++)
#pragma unroll
        for (int j = 0; j < 4; j++)
            As2[((rg << 2) + j) * 128 + (t << 4) + c16] = (_Float16)acc[t][j];
    __asm__ volatile("s_waitcnt lgkmcnt(0)" ::: "memory");
    const float4* As2v = (const float4*)As2;
    float4* featv = (float4*)feat;
#pragma unroll
    for (int ii = 0; ii < 4; ii++) {
        int ch = ii * 64 + lane;
        int row = row0 + (w << 4) + (ch >> 4);
        if (row < N) featv[(size_t)row * 16 + (ch & 15)] = As2v[ch];
    }
}

// Layer-2 residual + Layer-3 projections, fused; h3 never stored.
__global__ __launch_bounds__(256) void mfma_res_k(const _Float16* __restrict__ A,
                                                  const float4* __restrict__ Wf,
                                                  const _Float16* __restrict__ rsth,
                                                  const float* __restrict__ b2,
                                                  const float* __restrict__ W3,
                                                  const float* __restrict__ resW3,
                                                  const float* __restrict__ b3,
                                                  float* __restrict__ feat3,
                                                  float* __restrict__ res3, int N) {
    __shared__ float4 WsF[2048];
    __shared__ float4 AsF[1024];
    MFMA_STAGE_AND_LOOP()

    float4* As2v = (float4*)AsF + (w << 8);
#pragma unroll
    for (int ii = 0; ii < 4; ii++) {
        int ch = ii * 64 + lane;
        int row = row0 + (w << 4) + (ch >> 4);
        float4 v = make_float4(0.f, 0.f, 0.f, 0.f);
        if (row < N) v = ((const float4*)rsth)[(size_t)row * 16 + (ch & 15)];
        As2v[ch] = v;
    }
    __asm__ volatile("s_waitcnt lgkmcnt(0)" ::: "memory");
    const _Float16* As2 = (const _Float16*)As2v;

    float b2v[8];
#pragma unroll
    for (int t = 0; t < 8; t++) b2v[t] = b2[(t << 4) + c16];

    float hv[8][4];
#pragma unroll
    for (int t = 0; t < 8; t++)
#pragma unroll
        for (int j = 0; j < 4; j++) {
            float rv = (float)As2[((rg << 2) + j) * 128 + (t << 4) + c16];
            hv[t][j] = fmaxf(acc[t][j] + rv + b2v[t], 0.f);
        }

    float f3[4][6], r3[4][6];
#pragma unroll
    for (int j = 0; j < 4; j++)
#pragma unroll
        for (int h = 0; h < 6; h++) {
            f3[j][h] = 0.f;
            r3[j][h] = 0.f;
        }
#pragma unroll
    for (int t = 0; t < 8; t++) {
        int col = (t << 4) + c16;
        const float* w3p = W3 + col * 6;
        const float* rwp = resW3 + col * 6;
#pragma unroll
        for (int h = 0; h < 6; h++) {
            float w3 = w3p[h], rw = rwp[h];
#pragma unroll
            for (int j = 0; j < 4; j++) {
                f3[j][h] = fmaf(hv[t][j], w3, f3[j][h]);
                r3[j][h] = fmaf(hv[t][j], rw, r3[j][h]);
            }
        }
    }
#pragma unroll
    for (int m = 1; m < 16; m <<= 1)
#pragma unroll
        for (int j = 0; j < 4; j++)
#pragma unroll
            for (int h = 0; h < 6; h++) {
                f3[j][h] += __shfl_xor(f3[j][h], m);
                r3[j][h] += __shfl_xor(r3[j][h], m);
            }
    if (c16 == 0) {
#pragma unroll
        for (int j = 0; j < 4; j++) {
            int row = row0 + (w << 4) + (rg << 2) + j;
            if (row < N) {
#pragma unroll
                for (int h = 0; h < 6; h++) {
                    feat3[row * 6 + h] = f3[j][h];
                    res3[row * 6 + h] = r3[j][h] + b3[h];
                }
            }
        }
    }
}

// ---------------- Pull aggregation (H=4, D=32, fp16 in, fp16 out) ----------------
template <bool BR>
__global__ __launch_bounds__(256) void pull2_k(const int* __restrict__ row_beg,
                                               const int* __restrict__ row_end,
                                               const int* __restrict__ csr_src,
                                               const float* __restrict__ el,
                                               const float* __restrict__ er,
                                               const __half* __restrict__ feat_h,
                                               const float* __restrict__ bias,
                                               __half* __restrict__ outp, int N) {
    int n = (blockIdx.x << 2) + (threadIdx.x >> 6);
    if (n >= N) return;
    unsigned l = threadIdx.x & 63;
    unsigned h = l >> 4;
    float erd = er[((unsigned)n << 2) + h];
    const __half2* feat2 = (const __half2*)feat_h;
    int beg = __builtin_amdgcn_readfirstlane(row_beg[n]);
    int end = __builtin_amdgcn_readfirstlane(row_end[n]);
    float ax = 0.f, ay = 0.f, den = 0.f;
    int p = beg;
    for (; p + 4 <= end; p += 4) {
        int s0 = csr_src[p], s1 = csr_src[p + 1];
        int s2 = csr_src[p + 2], s3 = csr_src[p + 3];
        float e0 = el[((unsigned)s0 << 2) + h];
        float e1 = el[((unsigned)s1 << 2) + h];
        float e2 = el[((unsigned)s2 << 2) + h];
        float e3 = el[((unsigned)s3 << 2) + h];
        __half2 g0 = feat2[((unsigned)s0 << 6) + l];
        __half2 g1 = feat2[((unsigned)s1 << 6) + l];
        __half2 g2 = feat2[((unsigned)s2 << 6) + l];
        __half2 g3 = feat2[((unsigned)s3 << 6) + l];
        float x0 = e0 + erd, x1 = e1 + erd, x2 = e2 + erd, x3 = e3 + erd;
        x0 = fmaxf(x0, NEG * x0);
        x1 = fmaxf(x1, NEG * x1);
        x2 = fmaxf(x2, NEG * x2);
        x3 = fmaxf(x3, NEG * x3);
        float w0 = __expf(x0), w1 = __expf(x1), w2 = __expf(x2), w3 = __expf(x3);
        float2 f0 = __half22float2(g0), f1 = __half22float2(g1);
        float2 f2 = __half22float2(g2), f3 = __half22float2(g3);
        den += (w0 + w1) + (w2 + w3);
        ax = fmaf(w0, f0.x, ax);
        ay = fmaf(w0, f0.y, ay);
        ax = fmaf(w1, f1.x, ax);
        ay = fmaf(w1, f1.y, ay);
        ax = fmaf(w2, f2.x, ax);
        ay = fmaf(w2, f2.y, ay);
        ax = fmaf(w3, f3.x, ax);
        ay = fmaf(w3, f3.y, ay);
    }
    for (; p < end; p++) {
        int s0 = csr_src[p];
        float e0 = el[((unsigned)s0 << 2) + h];
        __half2 g0 = feat2[((unsigned)s0 << 6) + l];
        float x0 = e0 + erd;
        x0 = fmaxf(x0, NEG * x0);
        float w0 = __expf(x0);
        float2 f0 = __half22float2(g0);
        den += w0;
        ax = fmaf(w0, f0.x, ax);
        ay = fmaf(w0, f0.y, ay);
    }
    float inv = 1.f / den;  // den >= 1 edge (self-loops)
    float vx = ax * inv, vy = ay * inv;
    if (BR) {
        float2 b = ((const float2*)bias)[l];
        vx = fmaxf(vx + b.x, 0.f);
        vy = fmaxf(vy + b.y, 0.f);
    }
    ((__half2*)outp)[((size_t)n << 6) + l] = __floats2half2_rn(vx, vy);
}

// Layer 3 pull + residual + head-mean, one thread per node (D=1, H=6).
__global__ __launch_bounds__(256) void pull6f_k(const int* __restrict__ row_beg,
                                                const int* __restrict__ row_end,
                                                const int* __restrict__ csr_src,
                                                const float* __restrict__ feat3,
                                                const float* __restrict__ al3,
                                                const float* __restrict__ ar3,
                                                const float* __restrict__ res3,
                                                float* __restrict__ out, int N) {
    int n = blockIdx.x * blockDim.x + threadIdx.x;
    if (n >= N) return;
    float a3[6], fdr[6], acc[6], den[6];
#pragma unroll
    for (int h = 0; h < 6; h++) {
        a3[h] = al3[h];
        fdr[h] = feat3[n * 6 + h] * ar3[h];
        acc[h] = 0.f;
        den[h] = 0.f;
    }
    int beg = row_beg[n], end = row_end[n];
    for (int p = beg; p < end; p++) {
        int s = csr_src[p];
#pragma unroll
        for (int h = 0; h < 6; h++) {
            float f = feat3[(unsigned)s * 6 + h];
            float x = fmaf(f, a3[h], fdr[h]);
            x = fmaxf(x, NEG * x);
            float w = __expf(x);
            den[h] += w;
            acc[h] = fmaf(w, f, acc[h]);
        }
    }
    float m = 0.f;
#pragma unroll
    for (int h = 0; h < 6; h++) m += acc[h] / den[h] + res3[n * 6 + h];
    out[n] = m * (1.f / 6.f);
}

extern "C" void kernel_launch(void* const* d_in, const int* in_sizes, int n_in,
                              void* d_out, int out_size, void* d_ws, size_t ws_size,
                              hipStream_t stream) {
    const float* x = (const float*)d_in[0];
    const int* src = (const int*)d_in[1];
    const int* dst = (const int*)d_in[2];
    const float* W1 = (const float*)d_in[3];
    const float* al1 = (const float*)d_in[4];
    const float* ar1 = (const float*)d_in[5];
    const float* b1 = (const float*)d_in[6];
    const float* W2 = (const float*)d_in[7];
    const float* al2 = (const float*)d_in[8];
    const float* ar2 = (const float*)d_in[9];
    const float* b2 = (const float*)d_in[10];
    const float* resW2 = (const float*)d_in[11];
    const float* W3 = (const float*)d_in[12];
    const float* al3 = (const float*)d_in[13];
    const float* ar3 = (const float*)d_in[14];
    const float* b3 = (const float*)d_in[15];
    const float* resW3 = (const float*)d_in[16];
    float* out = (float*)d_out;

    const int N = in_sizes[0] / 64;
    const int E = in_sizes[1];
    const int NB = (N + 127) >> BUCKET_SHIFT;

    // ---- workspace layout (float units) ----
    float* ws = (float*)d_ws;
    __half* featA = (__half*)ws;                     // N*128 fp16
    __half* h2h = (__half*)(ws + (size_t)N * 64);    // N*128 fp16 (layer-1 out)
    __half* rsth = (__half*)(ws + (size_t)N * 128);  // N*128 fp16 (layer-2 agg out)
    float* el = ws + (size_t)N * 192;                // N*4
    float* er = el + (size_t)N * 4;                  // N*4
    float* feat3 = el;                               // N*6 aliases el/er in layer 3
    float* res3 = ws + (size_t)N * 200;              // N*6
    float* W2f = res3 + (size_t)N * 6;               // 8192 (2048 float4)
    float* rW2f = W2f + 8192;                        // 8192
    int* ip = (int*)(rW2f + 8192);
    int* cursor = ip;                                // 512 (memset)
    int* row_beg = cursor + 512;                     // N
    int* row_end = row_beg + N;                      // N
    unsigned* part = (unsigned*)(row_end + N);       // NB*CAP
    int* csr_src = (int*)(part + (size_t)NB * CAP);  // NB*CAP

    const int gN = (N + 255) / 256;
    const int gN64 = (N + 63) / 64;
    const int gNw = (N + 3) / 4;
    const int gP = (E + PCHUNK - 1) / PCHUNK;

    hipMemsetAsync(cursor, 0, sizeof(int) * 512, stream);
    // Stage 1 (fused, independent): weight fragments + edge partition.
    stage1_k<<<16 + gP, 256, 0, stream>>>(W2, resW2, (float4*)W2f, (float4*)rW2f,
                                          src, dst, cursor, part, E, NB);
    // Stage 2 (fused, independent): bucket CSR + layer-1 GEMM.
    stage2_k<<<NB + gN64, 256, 0, stream>>>(cursor, part, csr_src, row_beg, row_end,
                                            NB, x, W1, al1, ar1, featA, el, er, N);

    // ---- Layer 1 pull ----
    pull2_k<true><<<gNw, 256, 0, stream>>>(row_beg, row_end, csr_src, el, er,
                                           featA, b1, h2h, N);

    // ---- Layer 2: MFMA GEMM + pull + fused residual/layer-3 projections ----
    mfma_el_k<<<gN64, 256, 0, stream>>>((const _Float16*)h2h, (const float4*)W2f,
                                        al2, ar2, (_Float16*)featA, el, er, N);
    pull2_k<false><<<gNw, 256, 0, stream>>>(row_beg, row_end, csr_src, el, er,
                                            featA, nullptr, rsth, N);
    mfma_res_k<<<gN64, 256, 0, stream>>>((const _Float16*)h2h, (const float4*)rW2f,
                                         (const _Float16*)rsth, b2, W3, resW3, b3,
                                         feat3, res3, N);

    // ---- Layer 3: pull + residual + mean (fused) ----
    pull6f_k<<<gN, 256, 0, stream>>>(row_beg, row_end, csr_src, feat3, al3, ar3,
                                     res3, out, N);
}